// Round 1
// baseline (2181.774 us; speedup 1.0000x reference)
//
#include <hip/hip_runtime.h>
#include <hip/hip_bf16.h>
#include <math.h>

typedef __bf16 bf16;
typedef bf16 bf16x8 __attribute__((ext_vector_type(8)));
typedef bf16 bf16x4v __attribute__((ext_vector_type(4)));
typedef float f32x4 __attribute__((ext_vector_type(4)));

typedef const __attribute__((address_space(1))) void* gp_t;
typedef __attribute__((address_space(3))) void* lp_t;

#define SB 512
#define DM 1024

// ---------------- embedding + sinusoidal PE ----------------
__global__ __launch_bounds__(256) void embed_kernel(
    const int* __restrict__ tokens, const float* __restrict__ emb,
    float* __restrict__ x)
{
  const int row = blockIdx.x;              // b*S + s
  const int s = row & (SB - 1);
  const int tok = tokens[row];
  const int c = threadIdx.x * 4;
  const float4 e = *(const float4*)&emb[(size_t)tok * DM + c];
  const float ev[4] = {e.x, e.y, e.z, e.w};
  float o[4];
#pragma unroll
  for (int u = 0; u < 4; ++u) {
    int i = c + u;
    int j = i & ~1;
    float freq = __expf(-9.210340371976184f * (float)j * (1.0f / (float)DM));
    float ang = (float)s * freq;
    float pe = ((i & 1) == 0) ? __sinf(ang) : __cosf(ang);
    o[u] = ev[u] * 32.0f + pe;             // sqrt(1024) = 32
  }
  *(float4*)&x[(size_t)row * DM + c] = make_float4(o[0], o[1], o[2], o[3]);
}

// ---------------- layernorm (one block per row, D=1024) ----------------
template<bool OUTBF>
__global__ __launch_bounds__(256) void ln_kernel(
    const float* __restrict__ x, const float* __restrict__ g,
    const float* __restrict__ b, bf16* __restrict__ outB,
    float* __restrict__ outF)
{
  __shared__ float red[8];
  const int row = blockIdx.x, tid = threadIdx.x;
  const float4 v = *(const float4*)&x[(size_t)row * DM + tid * 4];
  float s = v.x + v.y + v.z + v.w;
  float sq = v.x * v.x + v.y * v.y + v.z * v.z + v.w * v.w;
#pragma unroll
  for (int off = 32; off > 0; off >>= 1) {
    s  += __shfl_xor(s, off);
    sq += __shfl_xor(sq, off);
  }
  if ((tid & 63) == 0) { red[tid >> 6] = s; red[4 + (tid >> 6)] = sq; }
  __syncthreads();
  const float ts = red[0] + red[1] + red[2] + red[3];
  const float tq = red[4] + red[5] + red[6] + red[7];
  const float mean = ts * (1.0f / DM);
  const float var  = tq * (1.0f / DM) - mean * mean;
  const float rstd = rsqrtf(var + 1e-5f);
  const int c = tid * 4;
  const float4 gv = *(const float4*)&g[c];
  const float4 bv = *(const float4*)&b[c];
  const float o0 = (v.x - mean) * rstd * gv.x + bv.x;
  const float o1 = (v.y - mean) * rstd * gv.y + bv.y;
  const float o2 = (v.z - mean) * rstd * gv.z + bv.z;
  const float o3 = (v.w - mean) * rstd * gv.w + bv.w;
  if constexpr (OUTBF) {
    bf16x4v ov = {(bf16)o0, (bf16)o1, (bf16)o2, (bf16)o3};
    *(bf16x4v*)&outB[(size_t)row * DM + c] = ov;
  } else {
    *(float4*)&outF[(size_t)row * DM + c] = make_float4(o0, o1, o2, o3);
  }
}

// ---------------- weight transpose+convert: W[K,N] f32 -> Wt[N,K] bf16 ----------------
// grid (N/64, K/64), 256 threads. Coalesced reads AND writes via LDS tile.
__global__ __launch_bounds__(256) void wtrans_kernel(
    const float* __restrict__ W, bf16* __restrict__ Wt, int N, int K)
{
  __shared__ __attribute__((aligned(16))) bf16 T[64][72];  // +8 pad
  const int tid = threadIdx.x;
  const int n0 = blockIdx.x * 64;
  const int k0 = blockIdx.y * 64;
#pragma unroll
  for (int p = 0; p < 4; ++p) {
    const int flat = p * 1024 + tid * 4;
    const int kr = flat >> 6;          // 0..63
    const int nc = flat & 63;          // multiple of 4
    const float4 v = *(const float4*)&W[(size_t)(k0 + kr) * N + n0 + nc];
    T[nc + 0][kr] = (bf16)v.x;
    T[nc + 1][kr] = (bf16)v.y;
    T[nc + 2][kr] = (bf16)v.z;
    T[nc + 3][kr] = (bf16)v.w;
  }
  __syncthreads();
#pragma unroll
  for (int p = 0; p < 2; ++p) {
    const int flat = p * 2048 + tid * 8;
    const int nr = flat >> 6;          // 0..63
    const int kc = flat & 63;          // multiple of 8
    const bf16x8 v = *(const bf16x8*)&T[nr][kc];
    *(bf16x8*)&Wt[(size_t)(n0 + nr) * K + k0 + kc] = v;
  }
}

// ---------------- concat q/kv biases: bqkv[l][3072] ----------------
__global__ __launch_bounds__(256) void bias_concat_kernel(
    const float* __restrict__ bq, const float* __restrict__ bkv,
    float* __restrict__ bqkv)
{
  const int i = blockIdx.x * 256 + threadIdx.x;   // 6*3072
  const int l = i / 3072, j = i - l * 3072;
  bqkv[i] = (j < 1024) ? bq[l * 1024 + j] : bkv[l * 2048 + (j - 1024)];
}

// ---------------- GEMM (m97 structure): C[M,N] = A[M,K] @ Bt[N,K]^T ----------------
// 128x128 tile, BK=32, 256 threads = 4 waves (2x2), acc[4][4] per wave.
// Staging via global_load_lds width=16 (wave-uniform base + lane*16 layout).
template<bool RELU, bool RESID, bool OUTBF>
__global__ __launch_bounds__(256) void gemm128(
    const bf16* __restrict__ A, const bf16* __restrict__ Bt,
    const float* __restrict__ bias, const float* __restrict__ resid,
    bf16* __restrict__ outB, float* __restrict__ outF,
    int M, int N, int K)
{
  __shared__ __attribute__((aligned(16))) bf16 As[128][32];
  __shared__ __attribute__((aligned(16))) bf16 Bs[128][32];
  const int tid  = threadIdx.x;
  const int lane = tid & 63;
  const int w    = tid >> 6;
  const int quad = lane >> 4;
  const int l16  = lane & 15;
  const int wr = w >> 1, wc = w & 1;
  const int m0 = blockIdx.y * 128;
  const int n0 = blockIdx.x * 128;

  f32x4 acc[4][4] = {};

  // staging addresses: flat slot tid (+256) covers [row= flat>>2][kcol=(flat&3)*8]
  const int r0 = tid >> 2;
  const int kg = (tid & 3) << 3;
  const bf16* a0 = &A [(size_t)(m0 + r0)      * K + kg];
  const bf16* a1 = &A [(size_t)(m0 + 64 + r0) * K + kg];
  const bf16* b0 = &Bt[(size_t)(n0 + r0)      * K + kg];
  const bf16* b1 = &Bt[(size_t)(n0 + 64 + r0) * K + kg];
  bf16* asd0 = &As[0][0] + (size_t)tid * 8;
  bf16* asd1 = &As[0][0] + (size_t)(256 + tid) * 8;
  bf16* bsd0 = &Bs[0][0] + (size_t)tid * 8;
  bf16* bsd1 = &Bs[0][0] + (size_t)(256 + tid) * 8;

  for (int k0 = 0; k0 < K; k0 += 32) {
    __syncthreads();
    __builtin_amdgcn_global_load_lds((gp_t)(a0 + k0), (lp_t)asd0, 16, 0, 0);
    __builtin_amdgcn_global_load_lds((gp_t)(a1 + k0), (lp_t)asd1, 16, 0, 0);
    __builtin_amdgcn_global_load_lds((gp_t)(b0 + k0), (lp_t)bsd0, 16, 0, 0);
    __builtin_amdgcn_global_load_lds((gp_t)(b1 + k0), (lp_t)bsd1, 16, 0, 0);
    __syncthreads();

    bf16x8 af[4], bfg[4];
#pragma unroll
    for (int mt = 0; mt < 4; ++mt)
      af[mt] = *(const bf16x8*)&As[(wr << 6) + (mt << 4) + l16][quad << 3];
#pragma unroll
    for (int nt = 0; nt < 4; ++nt)
      bfg[nt] = *(const bf16x8*)&Bs[(wc << 6) + (nt << 4) + l16][quad << 3];
#pragma unroll
    for (int mt = 0; mt < 4; ++mt)
#pragma unroll
      for (int nt = 0; nt < 4; ++nt)
        acc[mt][nt] = __builtin_amdgcn_mfma_f32_16x16x32_bf16(af[mt], bfg[nt], acc[mt][nt], 0, 0, 0);
  }

  // epilogue: C/D layout col=lane&15, row=quad*4+r
  const int rbase = quad << 2;
#pragma unroll
  for (int nt = 0; nt < 4; ++nt) {
    const int col = n0 + (wc << 6) + (nt << 4) + l16;
    const float bb = bias[col];
#pragma unroll
    for (int mt = 0; mt < 4; ++mt) {
#pragma unroll
      for (int r = 0; r < 4; ++r) {
        const int row = m0 + (wr << 6) + (mt << 4) + rbase + r;
        float val = acc[mt][nt][r] + bb;
        if constexpr (RESID) val += resid[(size_t)row * N + col];
        if constexpr (RELU)  val = fmaxf(val, 0.f);
        if constexpr (OUTBF) outB[(size_t)row * N + col] = (bf16)val;
        else                 outF[(size_t)row * N + col] = val;
      }
    }
  }
}

// ---------------- split-K GEMM with f32 atomic accumulate ----------------
// out must be pre-initialized with the residual value (it is: x holds the
// residual stream). Each split adds its K-chunk partial; split 0 adds bias.
// Raises grid from 256 -> 256*SPLIT blocks: the (8,32) N=1024 GEMMs were
// occupancy-starved at 1 block/CU (MfmaUtil 13.8%, Occupancy 10.7%).
template<int SPLIT>
__global__ __launch_bounds__(256) void gemm128_atomic(
    const bf16* __restrict__ A, const bf16* __restrict__ Bt,
    const float* __restrict__ bias, float* __restrict__ out,
    int M, int N, int K)
{
  __shared__ __attribute__((aligned(16))) bf16 As[128][32];
  __shared__ __attribute__((aligned(16))) bf16 Bs[128][32];
  const int tid  = threadIdx.x;
  const int lane = tid & 63;
  const int w    = tid >> 6;
  const int quad = lane >> 4;
  const int l16  = lane & 15;
  const int wr = w >> 1, wc = w & 1;
  const int m0 = blockIdx.y * 128;
  const int n0 = blockIdx.x * 128;
  const int kspan = K / SPLIT;
  const int kbeg = blockIdx.z * kspan;

  f32x4 acc[4][4] = {};

  const int r0 = tid >> 2;
  const int kg = (tid & 3) << 3;
  const bf16* a0 = &A [(size_t)(m0 + r0)      * K + kg];
  const bf16* a1 = &A [(size_t)(m0 + 64 + r0) * K + kg];
  const bf16* b0 = &Bt[(size_t)(n0 + r0)      * K + kg];
  const bf16* b1 = &Bt[(size_t)(n0 + 64 + r0) * K + kg];
  bf16* asd0 = &As[0][0] + (size_t)tid * 8;
  bf16* asd1 = &As[0][0] + (size_t)(256 + tid) * 8;
  bf16* bsd0 = &Bs[0][0] + (size_t)tid * 8;
  bf16* bsd1 = &Bs[0][0] + (size_t)(256 + tid) * 8;

  for (int k0 = kbeg; k0 < kbeg + kspan; k0 += 32) {
    __syncthreads();
    __builtin_amdgcn_global_load_lds((gp_t)(a0 + k0), (lp_t)asd0, 16, 0, 0);
    __builtin_amdgcn_global_load_lds((gp_t)(a1 + k0), (lp_t)asd1, 16, 0, 0);
    __builtin_amdgcn_global_load_lds((gp_t)(b0 + k0), (lp_t)bsd0, 16, 0, 0);
    __builtin_amdgcn_global_load_lds((gp_t)(b1 + k0), (lp_t)bsd1, 16, 0, 0);
    __syncthreads();

    bf16x8 af[4], bfg[4];
#pragma unroll
    for (int mt = 0; mt < 4; ++mt)
      af[mt] = *(const bf16x8*)&As[(wr << 6) + (mt << 4) + l16][quad << 3];
#pragma unroll
    for (int nt = 0; nt < 4; ++nt)
      bfg[nt] = *(const bf16x8*)&Bs[(wc << 6) + (nt << 4) + l16][quad << 3];
#pragma unroll
    for (int mt = 0; mt < 4; ++mt)
#pragma unroll
      for (int nt = 0; nt < 4; ++nt)
        acc[mt][nt] = __builtin_amdgcn_mfma_f32_16x16x32_bf16(af[mt], bfg[nt], acc[mt][nt], 0, 0, 0);
  }

  const int rbase = quad << 2;
  const bool addb = (blockIdx.z == 0);
#pragma unroll
  for (int nt = 0; nt < 4; ++nt) {
    const int col = n0 + (wc << 6) + (nt << 4) + l16;
    const float bb = addb ? bias[col] : 0.0f;
#pragma unroll
    for (int mt = 0; mt < 4; ++mt) {
#pragma unroll
      for (int r = 0; r < 4; ++r) {
        const int row = m0 + (wr << 6) + (mt << 4) + rbase + r;
        __hip_atomic_fetch_add(&out[(size_t)row * N + col],
                               acc[mt][nt][r] + bb,
                               __ATOMIC_RELAXED, __HIP_MEMORY_SCOPE_AGENT);
      }
    }
  }
}

// ---------------- fused flash attention (packed qkv [4096][3072]) ----------------
// grid: (S/64 q-tiles, H, B); block 256 = 4 waves; wave w owns q rows 16w..16w+15.
__global__ __launch_bounds__(256) void attn_kernel(
    const bf16* __restrict__ qkv, const int* __restrict__ lengths,
    bf16* __restrict__ o)
{
  __shared__ __attribute__((aligned(16))) bf16 Qs[64][64];     // [q][d]
  __shared__ __attribute__((aligned(16))) bf16 Ks[64][64];     // [kk][d]
  __shared__ __attribute__((aligned(16))) bf16 Vt[64][64];     // [dv][kk]
  __shared__ __attribute__((aligned(16))) bf16 Ps[4][16][64];  // per-wave P

  const int tid  = threadIdx.x;
  const int lane = tid & 63;
  const int w    = tid >> 6;
  const int quad = lane >> 4;
  const int l16  = lane & 15;
  const int qt = blockIdx.x, hh = blockIdx.y, b = blockIdx.z;
  const int q0 = qt * 64;
  const int len = lengths[b];
  const float scale = 0.125f;  // 1/sqrt(64)

  // stage Q tile once
#pragma unroll
  for (int r = 0; r < 2; ++r) {
    const int slot = tid + 256 * r;
    const int row = slot >> 3, dg = (slot & 7) << 3;
    *(bf16x8*)&Qs[row][dg] =
        *(const bf16x8*)&qkv[(size_t)(b * SB + q0 + row) * 3072 + hh * 64 + dg];
  }

  f32x4 Oacc[4] = {};
  float m_i[4] = {-1e30f, -1e30f, -1e30f, -1e30f};
  float l_i[4] = {0.f, 0.f, 0.f, 0.f};

  for (int kt0 = 0; kt0 < SB; kt0 += 64) {
    if (kt0 >= len) break;   // block-uniform
    __syncthreads();
    // stage K tile [kk][d]
#pragma unroll
    for (int r = 0; r < 2; ++r) {
      const int slot = tid + 256 * r;
      const int row = slot >> 3, dg = (slot & 7) << 3;
      *(bf16x8*)&Ks[row][dg] =
          *(const bf16x8*)&qkv[(size_t)(b * SB + kt0 + row) * 3072 + 1024 + hh * 64 + dg];
    }
    // stage V transposed [dv][kk] (2 passes cover kk 0..63)
#pragma unroll
    for (int r = 0; r < 2; ++r) {
      const int dv = tid & 63;
      const int kg2 = ((tid >> 6) << 3) + (r << 5);
      bf16x8 vv;
#pragma unroll
      for (int u = 0; u < 8; ++u)
        vv[u] = qkv[(size_t)(b * SB + kt0 + kg2 + u) * 3072 + 2048 + hh * 64 + dv];
      *(bf16x8*)&Vt[dv][kg2] = vv;
    }
    __syncthreads();

    // S tile = Q @ K^T
    f32x4 s[4] = {};
#pragma unroll
    for (int ds = 0; ds < 2; ++ds) {
      const bf16x8 af = *(const bf16x8*)&Qs[(w << 4) + l16][(ds << 5) + (quad << 3)];
#pragma unroll
      for (int nt = 0; nt < 4; ++nt) {
        const bf16x8 bfr = *(const bf16x8*)&Ks[(nt << 4) + l16][(ds << 5) + (quad << 3)];
        s[nt] = __builtin_amdgcn_mfma_f32_16x16x32_bf16(af, bfr, s[nt], 0, 0, 0);
      }
    }
    // scale + key mask
#pragma unroll
    for (int nt = 0; nt < 4; ++nt) {
      const bool valid = (kt0 + (nt << 4) + l16) < len;
#pragma unroll
      for (int r = 0; r < 4; ++r)
        s[nt][r] = valid ? s[nt][r] * scale : -1e30f;
    }
    // row max
    float mt[4];
#pragma unroll
    for (int r = 0; r < 4; ++r)
      mt[r] = fmaxf(fmaxf(s[0][r], s[1][r]), fmaxf(s[2][r], s[3][r]));
#pragma unroll
    for (int off = 1; off < 16; off <<= 1)
#pragma unroll
      for (int r = 0; r < 4; ++r)
        mt[r] = fmaxf(mt[r], __shfl_xor(mt[r], off));
    float alpha[4];
#pragma unroll
    for (int r = 0; r < 4; ++r) {
      const float mn = fmaxf(m_i[r], mt[r]);
      alpha[r] = __expf(m_i[r] - mn);
      m_i[r] = mn;
    }
    // exponentiate + row sums
    float rs[4] = {0.f, 0.f, 0.f, 0.f};
#pragma unroll
    for (int nt = 0; nt < 4; ++nt)
#pragma unroll
      for (int r = 0; r < 4; ++r) {
        const float pe = __expf(s[nt][r] - m_i[r]);
        s[nt][r] = pe;
        rs[r] += pe;
      }
#pragma unroll
    for (int off = 1; off < 16; off <<= 1)
#pragma unroll
      for (int r = 0; r < 4; ++r)
        rs[r] += __shfl_xor(rs[r], off);
#pragma unroll
    for (int r = 0; r < 4; ++r) l_i[r] = l_i[r] * alpha[r] + rs[r];
    // P (C-layout) -> LDS (A-layout round trip), rescale O
#pragma unroll
    for (int nt = 0; nt < 4; ++nt)
#pragma unroll
      for (int r = 0; r < 4; ++r) {
        Ps[w][(quad << 2) + r][(nt << 4) + l16] = (bf16)s[nt][r];
        Oacc[nt][r] *= alpha[r];
      }
    __syncthreads();
    // O += P @ V
#pragma unroll
    for (int ks = 0; ks < 2; ++ks) {
      const bf16x8 af = *(const bf16x8*)&Ps[w][l16][(ks << 5) + (quad << 3)];
#pragma unroll
      for (int nt = 0; nt < 4; ++nt) {
        const bf16x8 bfr = *(const bf16x8*)&Vt[(nt << 4) + l16][(ks << 5) + (quad << 3)];
        Oacc[nt] = __builtin_amdgcn_mfma_f32_16x16x32_bf16(af, bfr, Oacc[nt], 0, 0, 0);
      }
    }
  }
  // epilogue
  float inv[4];
#pragma unroll
  for (int r = 0; r < 4; ++r) inv[r] = 1.0f / l_i[r];
#pragma unroll
  for (int nt = 0; nt < 4; ++nt)
#pragma unroll
    for (int r = 0; r < 4; ++r) {
      const int row = b * SB + q0 + (w << 4) + (quad << 2) + r;
      const int col = hh * 64 + (nt << 4) + l16;
      o[(size_t)row * 1024 + col] = (bf16)(Oacc[nt][r] * inv[r]);
    }
}

extern "C" void kernel_launch(void* const* d_in, const int* in_sizes, int n_in,
                              void* d_out, int out_size, void* d_ws, size_t ws_size,
                              hipStream_t stream) {
  const int*   tokens = (const int*)  d_in[0];
  const int*   lengths= (const int*)  d_in[1];
  const float* emb    = (const float*)d_in[2];
  const float* Wq     = (const float*)d_in[3];
  const float* bq     = (const float*)d_in[4];
  const float* Wkv    = (const float*)d_in[5];
  const float* bkv    = (const float*)d_in[6];
  const float* Wo     = (const float*)d_in[7];
  const float* bo     = (const float*)d_in[8];
  const float* lag    = (const float*)d_in[9];
  const float* lab    = (const float*)d_in[10];
  const float* W1     = (const float*)d_in[11];
  const float* b1     = (const float*)d_in[12];
  const float* W2     = (const float*)d_in[13];
  const float* b2     = (const float*)d_in[14];
  const float* lfg    = (const float*)d_in[15];  // ln_ffn_g
  const float* lfb    = (const float*)d_in[16];  // ln_ffn_b
  const float* lgf    = (const float*)d_in[17];  // ln_f_g
  const float* lbf    = (const float*)d_in[18];  // ln_f_b

  char* p = (char*)d_ws;
  float* x     = (float*)p; p += (size_t)4096 * 1024 * 4;   // residual f32 (16MB)
  bf16*  h     = (bf16*)p;  p += (size_t)4096 * 1024 * 2;   // LN out (8MB)
  bf16*  qkv   = (bf16*)p;  p += (size_t)4096 * 3072 * 2;   // fused QKV (24MB)
  bf16*  o     = (bf16*)p;  p += (size_t)4096 * 1024 * 2;   // attn out (8MB)
  bf16*  mid   = (bf16*)p;  p += (size_t)4096 * 4096 * 2;   // FFN mid (32MB)
  bf16*  wqkvt = (bf16*)p;  p += (size_t)3072 * 1024 * 2;   // Wqkv^T (6MB)
  bf16*  wot   = (bf16*)p;  p += (size_t)1024 * 1024 * 2;   // Wo^T (2MB)
  bf16*  w1t   = (bf16*)p;  p += (size_t)4096 * 1024 * 2;   // W1^T (8MB)
  bf16*  w2t   = (bf16*)p;  p += (size_t)1024 * 4096 * 2;   // W2^T (8MB)
  float* bqkv  = (float*)p; p += (size_t)6 * 3072 * 4;      // concat bias

  bias_concat_kernel<<<72, 256, 0, stream>>>(bq, bkv, bqkv);
  embed_kernel<<<4096, 256, 0, stream>>>(tokens, emb, x);

  for (int l = 0; l < 6; ++l) {
    // per-layer weight transpose+convert (bf16, [N][K])
    wtrans_kernel<<<dim3(16, 16), 256, 0, stream>>>(
        Wq + (size_t)l * 1024 * 1024, wqkvt, 1024, 1024);
    wtrans_kernel<<<dim3(32, 16), 256, 0, stream>>>(
        Wkv + (size_t)l * 1024 * 2048, wqkvt + (size_t)1024 * 1024, 2048, 1024);
    wtrans_kernel<<<dim3(16, 16), 256, 0, stream>>>(
        Wo + (size_t)l * 1024 * 1024, wot, 1024, 1024);
    wtrans_kernel<<<dim3(64, 16), 256, 0, stream>>>(
        W1 + (size_t)l * 1024 * 4096, w1t, 4096, 1024);
    wtrans_kernel<<<dim3(16, 64), 256, 0, stream>>>(
        W2 + (size_t)l * 4096 * 1024, w2t, 1024, 4096);

    ln_kernel<true><<<4096, 256, 0, stream>>>(
        x, lag + (size_t)l * 1024, lab + (size_t)l * 1024, h, nullptr);
    gemm128<false, false, true><<<dim3(24, 32), 256, 0, stream>>>(
        h, wqkvt, bqkv + (size_t)l * 3072, nullptr, qkv, nullptr, 4096, 3072, 1024);
    attn_kernel<<<dim3(8, 16, 8), 256, 0, stream>>>(qkv, lengths, o);
    // attn-out projection + residual: x += o @ Wo^T + bo  (split-K=2, atomic)
    gemm128_atomic<2><<<dim3(8, 32, 2), 256, 0, stream>>>(
        o, wot, bo + (size_t)l * 1024, x, 4096, 1024, 1024);
    ln_kernel<true><<<4096, 256, 0, stream>>>(
        x, lfg + (size_t)l * 1024, lfb + (size_t)l * 1024, h, nullptr);
    gemm128<true, false, true><<<dim3(32, 32), 256, 0, stream>>>(
        h, w1t, b1 + (size_t)l * 4096, nullptr, mid, nullptr, 4096, 4096, 1024);
    // FFN down projection + residual: x += mid @ W2^T + b2  (split-K=4, atomic)
    gemm128_atomic<4><<<dim3(8, 32, 4), 256, 0, stream>>>(
        mid, w2t, b2 + (size_t)l * 1024, x, 4096, 1024, 4096);
  }
  ln_kernel<false><<<4096, 256, 0, stream>>>(x, lgf, lbf, nullptr, (float*)d_out);
}

// Round 2
// 2055.888 us; speedup vs baseline: 1.0612x; 1.0612x over previous
//
#include <hip/hip_runtime.h>
#include <hip/hip_bf16.h>
#include <math.h>

typedef __bf16 bf16;
typedef bf16 bf16x8 __attribute__((ext_vector_type(8)));
typedef bf16 bf16x4v __attribute__((ext_vector_type(4)));
typedef float f32x4 __attribute__((ext_vector_type(4)));

typedef const __attribute__((address_space(1))) void* gp_t;
typedef __attribute__((address_space(3))) void* lp_t;

#define SB 512
#define DM 1024

// ---------------- embedding + sinusoidal PE ----------------
__global__ __launch_bounds__(256) void embed_kernel(
    const int* __restrict__ tokens, const float* __restrict__ emb,
    float* __restrict__ x)
{
  const int row = blockIdx.x;              // b*S + s
  const int s = row & (SB - 1);
  const int tok = tokens[row];
  const int c = threadIdx.x * 4;
  const float4 e = *(const float4*)&emb[(size_t)tok * DM + c];
  const float ev[4] = {e.x, e.y, e.z, e.w};
  float o[4];
#pragma unroll
  for (int u = 0; u < 4; ++u) {
    int i = c + u;
    int j = i & ~1;
    float freq = __expf(-9.210340371976184f * (float)j * (1.0f / (float)DM));
    float ang = (float)s * freq;
    float pe = ((i & 1) == 0) ? __sinf(ang) : __cosf(ang);
    o[u] = ev[u] * 32.0f + pe;             // sqrt(1024) = 32
  }
  *(float4*)&x[(size_t)row * DM + c] = make_float4(o[0], o[1], o[2], o[3]);
}

// ---------------- layernorm (one block per row, D=1024) ----------------
template<bool OUTBF>
__global__ __launch_bounds__(256) void ln_kernel(
    const float* __restrict__ x, const float* __restrict__ g,
    const float* __restrict__ b, bf16* __restrict__ outB,
    float* __restrict__ outF)
{
  __shared__ float red[8];
  const int row = blockIdx.x, tid = threadIdx.x;
  const float4 v = *(const float4*)&x[(size_t)row * DM + tid * 4];
  float s = v.x + v.y + v.z + v.w;
  float sq = v.x * v.x + v.y * v.y + v.z * v.z + v.w * v.w;
#pragma unroll
  for (int off = 32; off > 0; off >>= 1) {
    s  += __shfl_xor(s, off);
    sq += __shfl_xor(sq, off);
  }
  if ((tid & 63) == 0) { red[tid >> 6] = s; red[4 + (tid >> 6)] = sq; }
  __syncthreads();
  const float ts = red[0] + red[1] + red[2] + red[3];
  const float tq = red[4] + red[5] + red[6] + red[7];
  const float mean = ts * (1.0f / DM);
  const float var  = tq * (1.0f / DM) - mean * mean;
  const float rstd = rsqrtf(var + 1e-5f);
  const int c = tid * 4;
  const float4 gv = *(const float4*)&g[c];
  const float4 bv = *(const float4*)&b[c];
  const float o0 = (v.x - mean) * rstd * gv.x + bv.x;
  const float o1 = (v.y - mean) * rstd * gv.y + bv.y;
  const float o2 = (v.z - mean) * rstd * gv.z + bv.z;
  const float o3 = (v.w - mean) * rstd * gv.w + bv.w;
  if constexpr (OUTBF) {
    bf16x4v ov = {(bf16)o0, (bf16)o1, (bf16)o2, (bf16)o3};
    *(bf16x4v*)&outB[(size_t)row * DM + c] = ov;
  } else {
    *(float4*)&outF[(size_t)row * DM + c] = make_float4(o0, o1, o2, o3);
  }
}

// ---------------- weight transpose+convert: W[K,N] f32 -> Wt[N,K] bf16 ----------------
// grid (N/64, K/64), 256 threads. Coalesced reads AND writes via LDS tile.
__global__ __launch_bounds__(256) void wtrans_kernel(
    const float* __restrict__ W, bf16* __restrict__ Wt, int N, int K)
{
  __shared__ __attribute__((aligned(16))) bf16 T[64][72];  // +8 pad
  const int tid = threadIdx.x;
  const int n0 = blockIdx.x * 64;
  const int k0 = blockIdx.y * 64;
#pragma unroll
  for (int p = 0; p < 4; ++p) {
    const int flat = p * 1024 + tid * 4;
    const int kr = flat >> 6;          // 0..63
    const int nc = flat & 63;          // multiple of 4
    const float4 v = *(const float4*)&W[(size_t)(k0 + kr) * N + n0 + nc];
    T[nc + 0][kr] = (bf16)v.x;
    T[nc + 1][kr] = (bf16)v.y;
    T[nc + 2][kr] = (bf16)v.z;
    T[nc + 3][kr] = (bf16)v.w;
  }
  __syncthreads();
#pragma unroll
  for (int p = 0; p < 2; ++p) {
    const int flat = p * 2048 + tid * 8;
    const int nr = flat >> 6;          // 0..63
    const int kc = flat & 63;          // multiple of 8
    const bf16x8 v = *(const bf16x8*)&T[nr][kc];
    *(bf16x8*)&Wt[(size_t)(n0 + nr) * K + k0 + kc] = v;
  }
}

// ---------------- concat q/kv biases: bqkv[l][3072] ----------------
__global__ __launch_bounds__(256) void bias_concat_kernel(
    const float* __restrict__ bq, const float* __restrict__ bkv,
    float* __restrict__ bqkv)
{
  const int i = blockIdx.x * 256 + threadIdx.x;   // 6*3072
  const int l = i / 3072, j = i - l * 3072;
  bqkv[i] = (j < 1024) ? bq[l * 1024 + j] : bkv[l * 2048 + (j - 1024)];
}

// ---------------- GEMM (m97 structure): C[M,N] = A[M,K] @ Bt[N,K]^T ----------------
// 128x128 tile, BK=32, 256 threads = 4 waves (2x2), acc[4][4] per wave.
// Staging via global_load_lds width=16 (wave-uniform base + lane*16 layout).
// XCD-aware swizzle (T1): consecutive original linear block ids round-robin
// across the 8 XCDs; remap so each XCD owns a contiguous chunk with bx
// fastest -> the 8 co-resident blocks on one XCD share the same A M-panel
// through that XCD's private L2 instead of re-fetching it via L3/HBM 8x.
// All launches have nwg % 8 == 0 -> the simple chunked remap is bijective.
template<bool RELU, bool RESID, bool OUTBF>
__global__ __launch_bounds__(256) void gemm128(
    const bf16* __restrict__ A, const bf16* __restrict__ Bt,
    const float* __restrict__ bias, const float* __restrict__ resid,
    bf16* __restrict__ outB, float* __restrict__ outF,
    int M, int N, int K)
{
  __shared__ __attribute__((aligned(16))) bf16 As[128][32];
  __shared__ __attribute__((aligned(16))) bf16 Bs[128][32];
  const int tid  = threadIdx.x;
  const int lane = tid & 63;
  const int w    = tid >> 6;
  const int quad = lane >> 4;
  const int l16  = lane & 15;
  const int wr = w >> 1, wc = w & 1;

  // ---- XCD swizzle ----
  const int gx    = gridDim.x;
  const int nwg   = gx * gridDim.y;
  const int orig  = blockIdx.y * gx + blockIdx.x;
  const int chunk = nwg >> 3;
  const int nl    = (orig & 7) * chunk + (orig >> 3);
  const int m0 = (nl / gx) * 128;
  const int n0 = (nl % gx) * 128;

  f32x4 acc[4][4] = {};

  // staging addresses: flat slot tid (+256) covers [row= flat>>2][kcol=(flat&3)*8]
  const int r0 = tid >> 2;
  const int kg = (tid & 3) << 3;
  const bf16* a0 = &A [(size_t)(m0 + r0)      * K + kg];
  const bf16* a1 = &A [(size_t)(m0 + 64 + r0) * K + kg];
  const bf16* b0 = &Bt[(size_t)(n0 + r0)      * K + kg];
  const bf16* b1 = &Bt[(size_t)(n0 + 64 + r0) * K + kg];
  bf16* asd0 = &As[0][0] + (size_t)tid * 8;
  bf16* asd1 = &As[0][0] + (size_t)(256 + tid) * 8;
  bf16* bsd0 = &Bs[0][0] + (size_t)tid * 8;
  bf16* bsd1 = &Bs[0][0] + (size_t)(256 + tid) * 8;

  for (int k0 = 0; k0 < K; k0 += 32) {
    __syncthreads();
    __builtin_amdgcn_global_load_lds((gp_t)(a0 + k0), (lp_t)asd0, 16, 0, 0);
    __builtin_amdgcn_global_load_lds((gp_t)(a1 + k0), (lp_t)asd1, 16, 0, 0);
    __builtin_amdgcn_global_load_lds((gp_t)(b0 + k0), (lp_t)bsd0, 16, 0, 0);
    __builtin_amdgcn_global_load_lds((gp_t)(b1 + k0), (lp_t)bsd1, 16, 0, 0);
    __syncthreads();

    bf16x8 af[4], bfg[4];
#pragma unroll
    for (int mt = 0; mt < 4; ++mt)
      af[mt] = *(const bf16x8*)&As[(wr << 6) + (mt << 4) + l16][quad << 3];
#pragma unroll
    for (int nt = 0; nt < 4; ++nt)
      bfg[nt] = *(const bf16x8*)&Bs[(wc << 6) + (nt << 4) + l16][quad << 3];
#pragma unroll
    for (int mt = 0; mt < 4; ++mt)
#pragma unroll
      for (int nt = 0; nt < 4; ++nt)
        acc[mt][nt] = __builtin_amdgcn_mfma_f32_16x16x32_bf16(af[mt], bfg[nt], acc[mt][nt], 0, 0, 0);
  }

  // epilogue: C/D layout col=lane&15, row=quad*4+r
  const int rbase = quad << 2;
#pragma unroll
  for (int nt = 0; nt < 4; ++nt) {
    const int col = n0 + (wc << 6) + (nt << 4) + l16;
    const float bb = bias[col];
#pragma unroll
    for (int mt = 0; mt < 4; ++mt) {
#pragma unroll
      for (int r = 0; r < 4; ++r) {
        const int row = m0 + (wr << 6) + (mt << 4) + rbase + r;
        float val = acc[mt][nt][r] + bb;
        if constexpr (RESID) val += resid[(size_t)row * N + col];
        if constexpr (RELU)  val = fmaxf(val, 0.f);
        if constexpr (OUTBF) outB[(size_t)row * N + col] = (bf16)val;
        else                 outF[(size_t)row * N + col] = val;
      }
    }
  }
}

// ---------------- fused flash attention (packed qkv [4096][3072]) ----------------
// grid: (S/64 q-tiles, H, B); block 256 = 4 waves; wave w owns q rows 16w..16w+15.
__global__ __launch_bounds__(256) void attn_kernel(
    const bf16* __restrict__ qkv, const int* __restrict__ lengths,
    bf16* __restrict__ o)
{
  __shared__ __attribute__((aligned(16))) bf16 Qs[64][64];     // [q][d]
  __shared__ __attribute__((aligned(16))) bf16 Ks[64][64];     // [kk][d]
  __shared__ __attribute__((aligned(16))) bf16 Vt[64][64];     // [dv][kk]
  __shared__ __attribute__((aligned(16))) bf16 Ps[4][16][64];  // per-wave P

  const int tid  = threadIdx.x;
  const int lane = tid & 63;
  const int w    = tid >> 6;
  const int quad = lane >> 4;
  const int l16  = lane & 15;
  const int qt = blockIdx.x, hh = blockIdx.y, b = blockIdx.z;
  const int q0 = qt * 64;
  const int len = lengths[b];
  const float scale = 0.125f;  // 1/sqrt(64)

  // stage Q tile once
#pragma unroll
  for (int r = 0; r < 2; ++r) {
    const int slot = tid + 256 * r;
    const int row = slot >> 3, dg = (slot & 7) << 3;
    *(bf16x8*)&Qs[row][dg] =
        *(const bf16x8*)&qkv[(size_t)(b * SB + q0 + row) * 3072 + hh * 64 + dg];
  }

  f32x4 Oacc[4] = {};
  float m_i[4] = {-1e30f, -1e30f, -1e30f, -1e30f};
  float l_i[4] = {0.f, 0.f, 0.f, 0.f};

  for (int kt0 = 0; kt0 < SB; kt0 += 64) {
    if (kt0 >= len) break;   // block-uniform
    __syncthreads();
    // stage K tile [kk][d]
#pragma unroll
    for (int r = 0; r < 2; ++r) {
      const int slot = tid + 256 * r;
      const int row = slot >> 3, dg = (slot & 7) << 3;
      *(bf16x8*)&Ks[row][dg] =
          *(const bf16x8*)&qkv[(size_t)(b * SB + kt0 + row) * 3072 + 1024 + hh * 64 + dg];
    }
    // stage V transposed [dv][kk] (2 passes cover kk 0..63)
#pragma unroll
    for (int r = 0; r < 2; ++r) {
      const int dv = tid & 63;
      const int kg2 = ((tid >> 6) << 3) + (r << 5);
      bf16x8 vv;
#pragma unroll
      for (int u = 0; u < 8; ++u)
        vv[u] = qkv[(size_t)(b * SB + kt0 + kg2 + u) * 3072 + 2048 + hh * 64 + dv];
      *(bf16x8*)&Vt[dv][kg2] = vv;
    }
    __syncthreads();

    // S tile = Q @ K^T
    f32x4 s[4] = {};
#pragma unroll
    for (int ds = 0; ds < 2; ++ds) {
      const bf16x8 af = *(const bf16x8*)&Qs[(w << 4) + l16][(ds << 5) + (quad << 3)];
#pragma unroll
      for (int nt = 0; nt < 4; ++nt) {
        const bf16x8 bfr = *(const bf16x8*)&Ks[(nt << 4) + l16][(ds << 5) + (quad << 3)];
        s[nt] = __builtin_amdgcn_mfma_f32_16x16x32_bf16(af, bfr, s[nt], 0, 0, 0);
      }
    }
    // scale + key mask
#pragma unroll
    for (int nt = 0; nt < 4; ++nt) {
      const bool valid = (kt0 + (nt << 4) + l16) < len;
#pragma unroll
      for (int r = 0; r < 4; ++r)
        s[nt][r] = valid ? s[nt][r] * scale : -1e30f;
    }
    // row max
    float mt[4];
#pragma unroll
    for (int r = 0; r < 4; ++r)
      mt[r] = fmaxf(fmaxf(s[0][r], s[1][r]), fmaxf(s[2][r], s[3][r]));
#pragma unroll
    for (int off = 1; off < 16; off <<= 1)
#pragma unroll
      for (int r = 0; r < 4; ++r)
        mt[r] = fmaxf(mt[r], __shfl_xor(mt[r], off));
    float alpha[4];
#pragma unroll
    for (int r = 0; r < 4; ++r) {
      const float mn = fmaxf(m_i[r], mt[r]);
      alpha[r] = __expf(m_i[r] - mn);
      m_i[r] = mn;
    }
    // exponentiate + row sums
    float rs[4] = {0.f, 0.f, 0.f, 0.f};
#pragma unroll
    for (int nt = 0; nt < 4; ++nt)
#pragma unroll
      for (int r = 0; r < 4; ++r) {
        const float pe = __expf(s[nt][r] - m_i[r]);
        s[nt][r] = pe;
        rs[r] += pe;
      }
#pragma unroll
    for (int off = 1; off < 16; off <<= 1)
#pragma unroll
      for (int r = 0; r < 4; ++r)
        rs[r] += __shfl_xor(rs[r], off);
#pragma unroll
    for (int r = 0; r < 4; ++r) l_i[r] = l_i[r] * alpha[r] + rs[r];
    // P (C-layout) -> LDS (A-layout round trip), rescale O
#pragma unroll
    for (int nt = 0; nt < 4; ++nt)
#pragma unroll
      for (int r = 0; r < 4; ++r) {
        Ps[w][(quad << 2) + r][(nt << 4) + l16] = (bf16)s[nt][r];
        Oacc[nt][r] *= alpha[r];
      }
    __syncthreads();
    // O += P @ V
#pragma unroll
    for (int ks = 0; ks < 2; ++ks) {
      const bf16x8 af = *(const bf16x8*)&Ps[w][l16][(ks << 5) + (quad << 3)];
#pragma unroll
      for (int nt = 0; nt < 4; ++nt) {
        const bf16x8 bfr = *(const bf16x8*)&Vt[(nt << 4) + l16][(ks << 5) + (quad << 3)];
        Oacc[nt] = __builtin_amdgcn_mfma_f32_16x16x32_bf16(af, bfr, Oacc[nt], 0, 0, 0);
      }
    }
  }
  // epilogue
  float inv[4];
#pragma unroll
  for (int r = 0; r < 4; ++r) inv[r] = 1.0f / l_i[r];
#pragma unroll
  for (int nt = 0; nt < 4; ++nt)
#pragma unroll
    for (int r = 0; r < 4; ++r) {
      const int row = b * SB + q0 + (w << 4) + (quad << 2) + r;
      const int col = hh * 64 + (nt << 4) + l16;
      o[(size_t)row * 1024 + col] = (bf16)(Oacc[nt][r] * inv[r]);
    }
}

extern "C" void kernel_launch(void* const* d_in, const int* in_sizes, int n_in,
                              void* d_out, int out_size, void* d_ws, size_t ws_size,
                              hipStream_t stream) {
  const int*   tokens = (const int*)  d_in[0];
  const int*   lengths= (const int*)  d_in[1];
  const float* emb    = (const float*)d_in[2];
  const float* Wq     = (const float*)d_in[3];
  const float* bq     = (const float*)d_in[4];
  const float* Wkv    = (const float*)d_in[5];
  const float* bkv    = (const float*)d_in[6];
  const float* Wo     = (const float*)d_in[7];
  const float* bo     = (const float*)d_in[8];
  const float* lag    = (const float*)d_in[9];
  const float* lab    = (const float*)d_in[10];
  const float* W1     = (const float*)d_in[11];
  const float* b1     = (const float*)d_in[12];
  const float* W2     = (const float*)d_in[13];
  const float* b2     = (const float*)d_in[14];
  const float* lfg    = (const float*)d_in[15];  // ln_ffn_g
  const float* lfb    = (const float*)d_in[16];  // ln_ffn_b
  const float* lgf    = (const float*)d_in[17];  // ln_f_g
  const float* lbf    = (const float*)d_in[18];  // ln_f_b

  char* p = (char*)d_ws;
  float* x     = (float*)p; p += (size_t)4096 * 1024 * 4;   // residual f32 (16MB)
  bf16*  h     = (bf16*)p;  p += (size_t)4096 * 1024 * 2;   // LN out (8MB)
  bf16*  qkv   = (bf16*)p;  p += (size_t)4096 * 3072 * 2;   // fused QKV (24MB)
  bf16*  o     = (bf16*)p;  p += (size_t)4096 * 1024 * 2;   // attn out (8MB)
  bf16*  mid   = (bf16*)p;  p += (size_t)4096 * 4096 * 2;   // FFN mid (32MB)
  bf16*  wqkvt = (bf16*)p;  p += (size_t)3072 * 1024 * 2;   // Wqkv^T (6MB)
  bf16*  wot   = (bf16*)p;  p += (size_t)1024 * 1024 * 2;   // Wo^T (2MB)
  bf16*  w1t   = (bf16*)p;  p += (size_t)4096 * 1024 * 2;   // W1^T (8MB)
  bf16*  w2t   = (bf16*)p;  p += (size_t)1024 * 4096 * 2;   // W2^T (8MB)
  float* bqkv  = (float*)p; p += (size_t)6 * 3072 * 4;      // concat bias

  bias_concat_kernel<<<72, 256, 0, stream>>>(bq, bkv, bqkv);
  embed_kernel<<<4096, 256, 0, stream>>>(tokens, emb, x);

  for (int l = 0; l < 6; ++l) {
    // per-layer weight transpose+convert (bf16, [N][K])
    wtrans_kernel<<<dim3(16, 16), 256, 0, stream>>>(
        Wq + (size_t)l * 1024 * 1024, wqkvt, 1024, 1024);
    wtrans_kernel<<<dim3(32, 16), 256, 0, stream>>>(
        Wkv + (size_t)l * 1024 * 2048, wqkvt + (size_t)1024 * 1024, 2048, 1024);
    wtrans_kernel<<<dim3(16, 16), 256, 0, stream>>>(
        Wo + (size_t)l * 1024 * 1024, wot, 1024, 1024);
    wtrans_kernel<<<dim3(64, 16), 256, 0, stream>>>(
        W1 + (size_t)l * 1024 * 4096, w1t, 4096, 1024);
    wtrans_kernel<<<dim3(16, 64), 256, 0, stream>>>(
        W2 + (size_t)l * 4096 * 1024, w2t, 1024, 4096);

    ln_kernel<true><<<4096, 256, 0, stream>>>(
        x, lag + (size_t)l * 1024, lab + (size_t)l * 1024, h, nullptr);
    gemm128<false, false, true><<<dim3(24, 32), 256, 0, stream>>>(
        h, wqkvt, bqkv + (size_t)l * 3072, nullptr, qkv, nullptr, 4096, 3072, 1024);
    attn_kernel<<<dim3(8, 16, 8), 256, 0, stream>>>(qkv, lengths, o);
    gemm128<false, true, false><<<dim3(8, 32), 256, 0, stream>>>(
        o, wot, bo + (size_t)l * 1024, x, nullptr, x, 4096, 1024, 1024);
    ln_kernel<true><<<4096, 256, 0, stream>>>(
        x, lfg + (size_t)l * 1024, lfb + (size_t)l * 1024, h, nullptr);
    gemm128<true, false, true><<<dim3(32, 32), 256, 0, stream>>>(
        h, w1t, b1 + (size_t)l * 4096, nullptr, mid, nullptr, 4096, 4096, 1024);
    gemm128<false, true, false><<<dim3(8, 32), 256, 0, stream>>>(
        mid, w2t, b2 + (size_t)l * 1024, x, nullptr, x, 4096, 1024, 4096);
  }
  ln_kernel<false><<<4096, 256, 0, stream>>>(x, lgf, lbf, nullptr, (float*)d_out);
}

// Round 3
// 1933.346 us; speedup vs baseline: 1.1285x; 1.0634x over previous
//
#include <hip/hip_runtime.h>
#include <hip/hip_bf16.h>
#include <math.h>

typedef __bf16 bf16;
typedef bf16 bf16x8 __attribute__((ext_vector_type(8)));
typedef bf16 bf16x4v __attribute__((ext_vector_type(4)));
typedef float f32x4 __attribute__((ext_vector_type(4)));

typedef const __attribute__((address_space(1))) void* gp_t;
typedef __attribute__((address_space(3))) void* lp_t;

#define SB 512
#define DM 1024

// ---------------- embedding + sinusoidal PE ----------------
__global__ __launch_bounds__(256) void embed_kernel(
    const int* __restrict__ tokens, const float* __restrict__ emb,
    float* __restrict__ x)
{
  const int row = blockIdx.x;              // b*S + s
  const int s = row & (SB - 1);
  const int tok = tokens[row];
  const int c = threadIdx.x * 4;
  const float4 e = *(const float4*)&emb[(size_t)tok * DM + c];
  const float ev[4] = {e.x, e.y, e.z, e.w};
  float o[4];
#pragma unroll
  for (int u = 0; u < 4; ++u) {
    int i = c + u;
    int j = i & ~1;
    float freq = __expf(-9.210340371976184f * (float)j * (1.0f / (float)DM));
    float ang = (float)s * freq;
    float pe = ((i & 1) == 0) ? __sinf(ang) : __cosf(ang);
    o[u] = ev[u] * 32.0f + pe;             // sqrt(1024) = 32
  }
  *(float4*)&x[(size_t)row * DM + c] = make_float4(o[0], o[1], o[2], o[3]);
}

// ---------------- layernorm (one block per row, D=1024) ----------------
template<bool OUTBF>
__global__ __launch_bounds__(256) void ln_kernel(
    const float* __restrict__ x, const float* __restrict__ g,
    const float* __restrict__ b, bf16* __restrict__ outB,
    float* __restrict__ outF)
{
  __shared__ float red[8];
  const int row = blockIdx.x, tid = threadIdx.x;
  const float4 v = *(const float4*)&x[(size_t)row * DM + tid * 4];
  float s = v.x + v.y + v.z + v.w;
  float sq = v.x * v.x + v.y * v.y + v.z * v.z + v.w * v.w;
#pragma unroll
  for (int off = 32; off > 0; off >>= 1) {
    s  += __shfl_xor(s, off);
    sq += __shfl_xor(sq, off);
  }
  if ((tid & 63) == 0) { red[tid >> 6] = s; red[4 + (tid >> 6)] = sq; }
  __syncthreads();
  const float ts = red[0] + red[1] + red[2] + red[3];
  const float tq = red[4] + red[5] + red[6] + red[7];
  const float mean = ts * (1.0f / DM);
  const float var  = tq * (1.0f / DM) - mean * mean;
  const float rstd = rsqrtf(var + 1e-5f);
  const int c = tid * 4;
  const float4 gv = *(const float4*)&g[c];
  const float4 bv = *(const float4*)&b[c];
  const float o0 = (v.x - mean) * rstd * gv.x + bv.x;
  const float o1 = (v.y - mean) * rstd * gv.y + bv.y;
  const float o2 = (v.z - mean) * rstd * gv.z + bv.z;
  const float o3 = (v.w - mean) * rstd * gv.w + bv.w;
  if constexpr (OUTBF) {
    bf16x4v ov = {(bf16)o0, (bf16)o1, (bf16)o2, (bf16)o3};
    *(bf16x4v*)&outB[(size_t)row * DM + c] = ov;
  } else {
    *(float4*)&outF[(size_t)row * DM + c] = make_float4(o0, o1, o2, o3);
  }
}

// ---------------- fused split-K reduce + residual + bias + layernorm ----------------
// x_new = x + sum_{z<NS} part[z] + badd;  optionally write x_new back to xout;
// then LN(x_new; g,b) -> bf16 h or f32 out. One block per row (M=4096, D=1024).
template<int NS, bool OUTBF, bool WRITEX>
__global__ __launch_bounds__(256) void red_ln_kernel(
    const float* __restrict__ x, const float* __restrict__ part,
    const float* __restrict__ badd, const float* __restrict__ g,
    const float* __restrict__ b, float* __restrict__ xout,
    bf16* __restrict__ outB, float* __restrict__ outF)
{
  __shared__ float red[8];
  const int row = blockIdx.x, tid = threadIdx.x;
  const int c = tid * 4;
  const size_t base = (size_t)row * DM + c;
  float4 v = *(const float4*)&x[base];
  const float4 ba = *(const float4*)&badd[c];
  v.x += ba.x; v.y += ba.y; v.z += ba.z; v.w += ba.w;
#pragma unroll
  for (int z = 0; z < NS; ++z) {
    const float4 pv = *(const float4*)&part[(size_t)z * 4096 * DM + base];
    v.x += pv.x; v.y += pv.y; v.z += pv.z; v.w += pv.w;
  }
  if constexpr (WRITEX) *(float4*)&xout[base] = v;
  float s = v.x + v.y + v.z + v.w;
  float sq = v.x * v.x + v.y * v.y + v.z * v.z + v.w * v.w;
#pragma unroll
  for (int off = 32; off > 0; off >>= 1) {
    s  += __shfl_xor(s, off);
    sq += __shfl_xor(sq, off);
  }
  if ((tid & 63) == 0) { red[tid >> 6] = s; red[4 + (tid >> 6)] = sq; }
  __syncthreads();
  const float ts = red[0] + red[1] + red[2] + red[3];
  const float tq = red[4] + red[5] + red[6] + red[7];
  const float mean = ts * (1.0f / DM);
  const float var  = tq * (1.0f / DM) - mean * mean;
  const float rstd = rsqrtf(var + 1e-5f);
  const float4 gv = *(const float4*)&g[c];
  const float4 bv = *(const float4*)&b[c];
  const float o0 = (v.x - mean) * rstd * gv.x + bv.x;
  const float o1 = (v.y - mean) * rstd * gv.y + bv.y;
  const float o2 = (v.z - mean) * rstd * gv.z + bv.z;
  const float o3 = (v.w - mean) * rstd * gv.w + bv.w;
  if constexpr (OUTBF) {
    bf16x4v ov = {(bf16)o0, (bf16)o1, (bf16)o2, (bf16)o3};
    *(bf16x4v*)&outB[(size_t)row * DM + c] = ov;
  } else {
    *(float4*)&outF[(size_t)row * DM + c] = make_float4(o0, o1, o2, o3);
  }
}

// ---------------- weight transpose+convert: W[K,N] f32 -> Wt[N,K] bf16 ----------------
__global__ __launch_bounds__(256) void wtrans_kernel(
    const float* __restrict__ W, bf16* __restrict__ Wt, int N, int K)
{
  __shared__ __attribute__((aligned(16))) bf16 T[64][72];  // +8 pad
  const int tid = threadIdx.x;
  const int n0 = blockIdx.x * 64;
  const int k0 = blockIdx.y * 64;
#pragma unroll
  for (int p = 0; p < 4; ++p) {
    const int flat = p * 1024 + tid * 4;
    const int kr = flat >> 6;          // 0..63
    const int nc = flat & 63;          // multiple of 4
    const float4 v = *(const float4*)&W[(size_t)(k0 + kr) * N + n0 + nc];
    T[nc + 0][kr] = (bf16)v.x;
    T[nc + 1][kr] = (bf16)v.y;
    T[nc + 2][kr] = (bf16)v.z;
    T[nc + 3][kr] = (bf16)v.w;
  }
  __syncthreads();
#pragma unroll
  for (int p = 0; p < 2; ++p) {
    const int flat = p * 2048 + tid * 8;
    const int nr = flat >> 6;          // 0..63
    const int kc = flat & 63;          // multiple of 8
    const bf16x8 v = *(const bf16x8*)&T[nr][kc];
    *(bf16x8*)&Wt[(size_t)(n0 + nr) * K + k0 + kc] = v;
  }
}

// ---------------- concat q/kv biases: bqkv[l][3072] ----------------
__global__ __launch_bounds__(256) void bias_concat_kernel(
    const float* __restrict__ bq, const float* __restrict__ bkv,
    float* __restrict__ bqkv)
{
  const int i = blockIdx.x * 256 + threadIdx.x;   // 6*3072
  const int l = i / 3072, j = i - l * 3072;
  bqkv[i] = (j < 1024) ? bq[l * 1024 + j] : bkv[l * 2048 + (j - 1024)];
}

// ---------------- GEMM (m97 structure): C[M,N] = A[M,K] @ Bt[N,K]^T ----------------
// 128x128 tile, BK=32, 256 threads = 4 waves (2x2), acc[4][4] per wave.
// XCD-aware swizzle (T1) keeps co-resident blocks' panels in one XCD's L2
// (round 2: FETCH_SIZE dropped to the ideal byte count).
// SPLITK: gridDim.z splits the K range; each split writes an f32 partial
// slice at z*M*N (no bias/resid/relu) -- reduced later in red_ln_kernel.
template<bool RELU, bool RESID, bool OUTBF, bool SPLITK>
__global__ __launch_bounds__(256) void gemm128(
    const bf16* __restrict__ A, const bf16* __restrict__ Bt,
    const float* __restrict__ bias, const float* __restrict__ resid,
    bf16* __restrict__ outB, float* __restrict__ outF,
    int M, int N, int K)
{
  __shared__ __attribute__((aligned(16))) bf16 As[128][32];
  __shared__ __attribute__((aligned(16))) bf16 Bs[128][32];
  const int tid  = threadIdx.x;
  const int lane = tid & 63;
  const int w    = tid >> 6;
  const int quad = lane >> 4;
  const int l16  = lane & 15;
  const int wr = w >> 1, wc = w & 1;

  // ---- XCD swizzle (per z-slice; nwg % 8 == 0 for all launches) ----
  const int gx    = gridDim.x;
  const int nwg   = gx * gridDim.y;
  const int orig  = blockIdx.y * gx + blockIdx.x;
  const int chunk = nwg >> 3;
  const int nl    = (orig & 7) * chunk + (orig >> 3);
  const int m0 = (nl / gx) * 128;
  const int n0 = (nl % gx) * 128;

  const int kspan = K / (int)gridDim.z;
  const int kbeg  = blockIdx.z * kspan;

  f32x4 acc[4][4] = {};

  // staging addresses: flat slot tid (+256) covers [row= flat>>2][kcol=(flat&3)*8]
  const int r0 = tid >> 2;
  const int kg = (tid & 3) << 3;
  const bf16* a0 = &A [(size_t)(m0 + r0)      * K + kg];
  const bf16* a1 = &A [(size_t)(m0 + 64 + r0) * K + kg];
  const bf16* b0 = &Bt[(size_t)(n0 + r0)      * K + kg];
  const bf16* b1 = &Bt[(size_t)(n0 + 64 + r0) * K + kg];
  bf16* asd0 = &As[0][0] + (size_t)tid * 8;
  bf16* asd1 = &As[0][0] + (size_t)(256 + tid) * 8;
  bf16* bsd0 = &Bs[0][0] + (size_t)tid * 8;
  bf16* bsd1 = &Bs[0][0] + (size_t)(256 + tid) * 8;

  for (int k0 = kbeg; k0 < kbeg + kspan; k0 += 32) {
    __syncthreads();
    __builtin_amdgcn_global_load_lds((gp_t)(a0 + k0), (lp_t)asd0, 16, 0, 0);
    __builtin_amdgcn_global_load_lds((gp_t)(a1 + k0), (lp_t)asd1, 16, 0, 0);
    __builtin_amdgcn_global_load_lds((gp_t)(b0 + k0), (lp_t)bsd0, 16, 0, 0);
    __builtin_amdgcn_global_load_lds((gp_t)(b1 + k0), (lp_t)bsd1, 16, 0, 0);
    __syncthreads();

    bf16x8 af[4], bfg[4];
#pragma unroll
    for (int mt = 0; mt < 4; ++mt)
      af[mt] = *(const bf16x8*)&As[(wr << 6) + (mt << 4) + l16][quad << 3];
#pragma unroll
    for (int nt = 0; nt < 4; ++nt)
      bfg[nt] = *(const bf16x8*)&Bs[(wc << 6) + (nt << 4) + l16][quad << 3];
#pragma unroll
    for (int mt = 0; mt < 4; ++mt)
#pragma unroll
      for (int nt = 0; nt < 4; ++nt)
        acc[mt][nt] = __builtin_amdgcn_mfma_f32_16x16x32_bf16(af[mt], bfg[nt], acc[mt][nt], 0, 0, 0);
  }

  // epilogue: C/D layout col=lane&15, row=quad*4+r
  const int rbase = quad << 2;
  const size_t zoff = (size_t)blockIdx.z * M * N;
#pragma unroll
  for (int nt = 0; nt < 4; ++nt) {
    const int col = n0 + (wc << 6) + (nt << 4) + l16;
    const float bb = SPLITK ? 0.0f : bias[col];
#pragma unroll
    for (int mt = 0; mt < 4; ++mt) {
#pragma unroll
      for (int r = 0; r < 4; ++r) {
        const int row = m0 + (wr << 6) + (mt << 4) + rbase + r;
        float val = acc[mt][nt][r] + bb;
        if constexpr (SPLITK) {
          outF[zoff + (size_t)row * N + col] = val;
        } else {
          if constexpr (RESID) val += resid[(size_t)row * N + col];
          if constexpr (RELU)  val = fmaxf(val, 0.f);
          if constexpr (OUTBF) outB[(size_t)row * N + col] = (bf16)val;
          else                 outF[(size_t)row * N + col] = val;
        }
      }
    }
  }
}

// ---------------- fused flash attention (packed qkv [4096][3072]) ----------------
__global__ __launch_bounds__(256) void attn_kernel(
    const bf16* __restrict__ qkv, const int* __restrict__ lengths,
    bf16* __restrict__ o)
{
  __shared__ __attribute__((aligned(16))) bf16 Qs[64][64];     // [q][d]
  __shared__ __attribute__((aligned(16))) bf16 Ks[64][64];     // [kk][d]
  __shared__ __attribute__((aligned(16))) bf16 Vt[64][64];     // [dv][kk]
  __shared__ __attribute__((aligned(16))) bf16 Ps[4][16][64];  // per-wave P

  const int tid  = threadIdx.x;
  const int lane = tid & 63;
  const int w    = tid >> 6;
  const int quad = lane >> 4;
  const int l16  = lane & 15;
  const int qt = blockIdx.x, hh = blockIdx.y, b = blockIdx.z;
  const int q0 = qt * 64;
  const int len = lengths[b];
  const float scale = 0.125f;  // 1/sqrt(64)

  // stage Q tile once
#pragma unroll
  for (int r = 0; r < 2; ++r) {
    const int slot = tid + 256 * r;
    const int row = slot >> 3, dg = (slot & 7) << 3;
    *(bf16x8*)&Qs[row][dg] =
        *(const bf16x8*)&qkv[(size_t)(b * SB + q0 + row) * 3072 + hh * 64 + dg];
  }

  f32x4 Oacc[4] = {};
  float m_i[4] = {-1e30f, -1e30f, -1e30f, -1e30f};
  float l_i[4] = {0.f, 0.f, 0.f, 0.f};

  for (int kt0 = 0; kt0 < SB; kt0 += 64) {
    if (kt0 >= len) break;   // block-uniform
    __syncthreads();
    // stage K tile [kk][d]
#pragma unroll
    for (int r = 0; r < 2; ++r) {
      const int slot = tid + 256 * r;
      const int row = slot >> 3, dg = (slot & 7) << 3;
      *(bf16x8*)&Ks[row][dg] =
          *(const bf16x8*)&qkv[(size_t)(b * SB + kt0 + row) * 3072 + 1024 + hh * 64 + dg];
    }
    // stage V transposed [dv][kk]
#pragma unroll
    for (int r = 0; r < 2; ++r) {
      const int dv = tid & 63;
      const int kg2 = ((tid >> 6) << 3) + (r << 5);
      bf16x8 vv;
#pragma unroll
      for (int u = 0; u < 8; ++u)
        vv[u] = qkv[(size_t)(b * SB + kt0 + kg2 + u) * 3072 + 2048 + hh * 64 + dv];
      *(bf16x8*)&Vt[dv][kg2] = vv;
    }
    __syncthreads();

    // S tile = Q @ K^T
    f32x4 s[4] = {};
#pragma unroll
    for (int ds = 0; ds < 2; ++ds) {
      const bf16x8 af = *(const bf16x8*)&Qs[(w << 4) + l16][(ds << 5) + (quad << 3)];
#pragma unroll
      for (int nt = 0; nt < 4; ++nt) {
        const bf16x8 bfr = *(const bf16x8*)&Ks[(nt << 4) + l16][(ds << 5) + (quad << 3)];
        s[nt] = __builtin_amdgcn_mfma_f32_16x16x32_bf16(af, bfr, s[nt], 0, 0, 0);
      }
    }
    // scale + key mask
#pragma unroll
    for (int nt = 0; nt < 4; ++nt) {
      const bool valid = (kt0 + (nt << 4) + l16) < len;
#pragma unroll
      for (int r = 0; r < 4; ++r)
        s[nt][r] = valid ? s[nt][r] * scale : -1e30f;
    }
    // row max
    float mt[4];
#pragma unroll
    for (int r = 0; r < 4; ++r)
      mt[r] = fmaxf(fmaxf(s[0][r], s[1][r]), fmaxf(s[2][r], s[3][r]));
#pragma unroll
    for (int off = 1; off < 16; off <<= 1)
#pragma unroll
      for (int r = 0; r < 4; ++r)
        mt[r] = fmaxf(mt[r], __shfl_xor(mt[r], off));
    float alpha[4];
#pragma unroll
    for (int r = 0; r < 4; ++r) {
      const float mn = fmaxf(m_i[r], mt[r]);
      alpha[r] = __expf(m_i[r] - mn);
      m_i[r] = mn;
    }
    // exponentiate + row sums
    float rs[4] = {0.f, 0.f, 0.f, 0.f};
#pragma unroll
    for (int nt = 0; nt < 4; ++nt)
#pragma unroll
      for (int r = 0; r < 4; ++r) {
        const float pe = __expf(s[nt][r] - m_i[r]);
        s[nt][r] = pe;
        rs[r] += pe;
      }
#pragma unroll
    for (int off = 1; off < 16; off <<= 1)
#pragma unroll
      for (int r = 0; r < 4; ++r)
        rs[r] += __shfl_xor(rs[r], off);
#pragma unroll
    for (int r = 0; r < 4; ++r) l_i[r] = l_i[r] * alpha[r] + rs[r];
    // P (C-layout) -> LDS (A-layout round trip), rescale O
#pragma unroll
    for (int nt = 0; nt < 4; ++nt)
#pragma unroll
      for (int r = 0; r < 4; ++r) {
        Ps[w][(quad << 2) + r][(nt << 4) + l16] = (bf16)s[nt][r];
        Oacc[nt][r] *= alpha[r];
      }
    __syncthreads();
    // O += P @ V
#pragma unroll
    for (int ks = 0; ks < 2; ++ks) {
      const bf16x8 af = *(const bf16x8*)&Ps[w][l16][(ks << 5) + (quad << 3)];
#pragma unroll
      for (int nt = 0; nt < 4; ++nt) {
        const bf16x8 bfr = *(const bf16x8*)&Vt[(nt << 4) + l16][(ks << 5) + (quad << 3)];
        Oacc[nt] = __builtin_amdgcn_mfma_f32_16x16x32_bf16(af, bfr, Oacc[nt], 0, 0, 0);
      }
    }
  }
  // epilogue
  float inv[4];
#pragma unroll
  for (int r = 0; r < 4; ++r) inv[r] = 1.0f / l_i[r];
#pragma unroll
  for (int nt = 0; nt < 4; ++nt)
#pragma unroll
    for (int r = 0; r < 4; ++r) {
      const int row = b * SB + q0 + (w << 4) + (quad << 2) + r;
      const int col = hh * 64 + (nt << 4) + l16;
      o[(size_t)row * 1024 + col] = (bf16)(Oacc[nt][r] * inv[r]);
    }
}

extern "C" void kernel_launch(void* const* d_in, const int* in_sizes, int n_in,
                              void* d_out, int out_size, void* d_ws, size_t ws_size,
                              hipStream_t stream) {
  const int*   tokens = (const int*)  d_in[0];
  const int*   lengths= (const int*)  d_in[1];
  const float* emb    = (const float*)d_in[2];
  const float* Wq     = (const float*)d_in[3];
  const float* bq     = (const float*)d_in[4];
  const float* Wkv    = (const float*)d_in[5];
  const float* bkv    = (const float*)d_in[6];
  const float* Wo     = (const float*)d_in[7];
  const float* bo     = (const float*)d_in[8];
  const float* lag    = (const float*)d_in[9];
  const float* lab    = (const float*)d_in[10];
  const float* W1     = (const float*)d_in[11];
  const float* b1     = (const float*)d_in[12];
  const float* W2     = (const float*)d_in[13];
  const float* b2     = (const float*)d_in[14];
  const float* lfg    = (const float*)d_in[15];  // ln_ffn_g
  const float* lfb    = (const float*)d_in[16];  // ln_ffn_b
  const float* lgf    = (const float*)d_in[17];  // ln_f_g
  const float* lbf    = (const float*)d_in[18];  // ln_f_b

  char* p = (char*)d_ws;
  float* x     = (float*)p; p += (size_t)4096 * 1024 * 4;   // residual f32 (16MB)
  bf16*  h     = (bf16*)p;  p += (size_t)4096 * 1024 * 2;   // LN out (8MB)
  bf16*  qkv   = (bf16*)p;  p += (size_t)4096 * 3072 * 2;   // fused QKV (24MB)
  bf16*  o     = (bf16*)p;  p += (size_t)4096 * 1024 * 2;   // attn out (8MB)
  bf16*  mid   = (bf16*)p;  p += (size_t)4096 * 4096 * 2;   // FFN mid (32MB)
  bf16*  wqkvt = (bf16*)p;  p += (size_t)3072 * 1024 * 2;   // Wqkv^T (6MB)
  bf16*  wot   = (bf16*)p;  p += (size_t)1024 * 1024 * 2;   // Wo^T (2MB)
  bf16*  w1t   = (bf16*)p;  p += (size_t)4096 * 1024 * 2;   // W1^T (8MB)
  bf16*  w2t   = (bf16*)p;  p += (size_t)1024 * 4096 * 2;   // W2^T (8MB)
  float* bqkv  = (float*)p; p += (size_t)6 * 3072 * 4;      // concat bias
  p = (char*)(((size_t)p + 255) & ~(size_t)255);
  float* part  = (float*)p; p += (size_t)4 * 4096 * 1024 * 4; // split-K partials (64MB)

  bias_concat_kernel<<<72, 256, 0, stream>>>(bq, bkv, bqkv);
  embed_kernel<<<4096, 256, 0, stream>>>(tokens, emb, x);

  for (int l = 0; l < 6; ++l) {
    // per-layer weight transpose+convert (bf16, [N][K])
    wtrans_kernel<<<dim3(16, 16), 256, 0, stream>>>(
        Wq + (size_t)l * 1024 * 1024, wqkvt, 1024, 1024);
    wtrans_kernel<<<dim3(32, 16), 256, 0, stream>>>(
        Wkv + (size_t)l * 1024 * 2048, wqkvt + (size_t)1024 * 1024, 2048, 1024);
    wtrans_kernel<<<dim3(16, 16), 256, 0, stream>>>(
        Wo + (size_t)l * 1024 * 1024, wot, 1024, 1024);
    wtrans_kernel<<<dim3(64, 16), 256, 0, stream>>>(
        W1 + (size_t)l * 1024 * 4096, w1t, 4096, 1024);
    wtrans_kernel<<<dim3(16, 64), 256, 0, stream>>>(
        W2 + (size_t)l * 4096 * 1024, w2t, 1024, 4096);

    // --- attn sublayer ---
    if (l == 0) {
      ln_kernel<true><<<4096, 256, 0, stream>>>(
          x, lag, lab, h, nullptr);
    } else {
      // reduce previous layer's W2 partials (+b2_{l-1}) into x, then ln_attn
      red_ln_kernel<4, true, true><<<4096, 256, 0, stream>>>(
          x, part, b2 + (size_t)(l - 1) * 1024,
          lag + (size_t)l * 1024, lab + (size_t)l * 1024, x, h, nullptr);
    }
    gemm128<false, false, true, false><<<dim3(24, 32), 256, 0, stream>>>(
        h, wqkvt, bqkv + (size_t)l * 3072, nullptr, qkv, nullptr, 4096, 3072, 1024);
    attn_kernel<<<dim3(8, 16, 8), 256, 0, stream>>>(qkv, lengths, o);
    // attn-out projection, split-K=2 -> partials (grid 512 = 2 blocks/CU)
    gemm128<false, false, false, true><<<dim3(8, 32, 2), 256, 0, stream>>>(
        o, wot, nullptr, nullptr, nullptr, part, 4096, 1024, 1024);
    // --- FFN sublayer ---
    // reduce Wo partials (+bo) into x, then ln_ffn
    red_ln_kernel<2, true, true><<<4096, 256, 0, stream>>>(
        x, part, bo + (size_t)l * 1024,
        lfg + (size_t)l * 1024, lfb + (size_t)l * 1024, x, h, nullptr);
    gemm128<true, false, true, false><<<dim3(32, 32), 256, 0, stream>>>(
        h, w1t, b1 + (size_t)l * 4096, nullptr, mid, nullptr, 4096, 4096, 1024);
    // FFN down projection, split-K=4 -> partials (grid 1024 = 4 blocks/CU)
    gemm128<false, false, false, true><<<dim3(8, 32, 4), 256, 0, stream>>>(
        mid, w2t, nullptr, nullptr, nullptr, part, 4096, 1024, 4096);
  }
  // final: reduce layer-5 W2 partials (+b2_5) and apply ln_f -> d_out (f32)
  red_ln_kernel<4, false, false><<<4096, 256, 0, stream>>>(
      x, part, b2 + (size_t)5 * 1024, lgf, lbf, nullptr, nullptr, (float*)d_out);
}

// Round 4
// 1892.512 us; speedup vs baseline: 1.1528x; 1.0216x over previous
//
#include <hip/hip_runtime.h>
#include <hip/hip_bf16.h>
#include <math.h>

typedef __bf16 bf16;
typedef bf16 bf16x8 __attribute__((ext_vector_type(8)));
typedef bf16 bf16x4v __attribute__((ext_vector_type(4)));
typedef float f32x4 __attribute__((ext_vector_type(4)));

typedef const __attribute__((address_space(1))) void* gp_t;
typedef __attribute__((address_space(3))) void* lp_t;

#define SB 512
#define DM 1024

// ---------------- embedding + sinusoidal PE ----------------
__global__ __launch_bounds__(256) void embed_kernel(
    const int* __restrict__ tokens, const float* __restrict__ emb,
    float* __restrict__ x)
{
  const int row = blockIdx.x;              // b*S + s
  const int s = row & (SB - 1);
  const int tok = tokens[row];
  const int c = threadIdx.x * 4;
  const float4 e = *(const float4*)&emb[(size_t)tok * DM + c];
  const float ev[4] = {e.x, e.y, e.z, e.w};
  float o[4];
#pragma unroll
  for (int u = 0; u < 4; ++u) {
    int i = c + u;
    int j = i & ~1;
    float freq = __expf(-9.210340371976184f * (float)j * (1.0f / (float)DM));
    float ang = (float)s * freq;
    float pe = ((i & 1) == 0) ? __sinf(ang) : __cosf(ang);
    o[u] = ev[u] * 32.0f + pe;             // sqrt(1024) = 32
  }
  *(float4*)&x[(size_t)row * DM + c] = make_float4(o[0], o[1], o[2], o[3]);
}

// ---------------- layernorm (one block per row, D=1024) ----------------
template<bool OUTBF>
__global__ __launch_bounds__(256) void ln_kernel(
    const float* __restrict__ x, const float* __restrict__ g,
    const float* __restrict__ b, bf16* __restrict__ outB,
    float* __restrict__ outF)
{
  __shared__ float red[8];
  const int row = blockIdx.x, tid = threadIdx.x;
  const float4 v = *(const float4*)&x[(size_t)row * DM + tid * 4];
  float s = v.x + v.y + v.z + v.w;
  float sq = v.x * v.x + v.y * v.y + v.z * v.z + v.w * v.w;
#pragma unroll
  for (int off = 32; off > 0; off >>= 1) {
    s  += __shfl_xor(s, off);
    sq += __shfl_xor(sq, off);
  }
  if ((tid & 63) == 0) { red[tid >> 6] = s; red[4 + (tid >> 6)] = sq; }
  __syncthreads();
  const float ts = red[0] + red[1] + red[2] + red[3];
  const float tq = red[4] + red[5] + red[6] + red[7];
  const float mean = ts * (1.0f / DM);
  const float var  = tq * (1.0f / DM) - mean * mean;
  const float rstd = rsqrtf(var + 1e-5f);
  const int c = tid * 4;
  const float4 gv = *(const float4*)&g[c];
  const float4 bv = *(const float4*)&b[c];
  const float o0 = (v.x - mean) * rstd * gv.x + bv.x;
  const float o1 = (v.y - mean) * rstd * gv.y + bv.y;
  const float o2 = (v.z - mean) * rstd * gv.z + bv.z;
  const float o3 = (v.w - mean) * rstd * gv.w + bv.w;
  if constexpr (OUTBF) {
    bf16x4v ov = {(bf16)o0, (bf16)o1, (bf16)o2, (bf16)o3};
    *(bf16x4v*)&outB[(size_t)row * DM + c] = ov;
  } else {
    *(float4*)&outF[(size_t)row * DM + c] = make_float4(o0, o1, o2, o3);
  }
}

// ---------------- fused split-K reduce + residual + bias + layernorm ----------------
// x_new = x + sum_{z<NS} part[z] + badd;  optionally write x_new back to xout;
// then LN(x_new; g,b) -> bf16 h or f32 out. One block per row (M=4096, D=1024).
template<int NS, bool OUTBF, bool WRITEX>
__global__ __launch_bounds__(256) void red_ln_kernel(
    const float* __restrict__ x, const float* __restrict__ part,
    const float* __restrict__ badd, const float* __restrict__ g,
    const float* __restrict__ b, float* __restrict__ xout,
    bf16* __restrict__ outB, float* __restrict__ outF)
{
  __shared__ float red[8];
  const int row = blockIdx.x, tid = threadIdx.x;
  const int c = tid * 4;
  const size_t base = (size_t)row * DM + c;
  float4 v = *(const float4*)&x[base];
  const float4 ba = *(const float4*)&badd[c];
  v.x += ba.x; v.y += ba.y; v.z += ba.z; v.w += ba.w;
#pragma unroll
  for (int z = 0; z < NS; ++z) {
    const float4 pv = *(const float4*)&part[(size_t)z * 4096 * DM + base];
    v.x += pv.x; v.y += pv.y; v.z += pv.z; v.w += pv.w;
  }
  if constexpr (WRITEX) *(float4*)&xout[base] = v;
  float s = v.x + v.y + v.z + v.w;
  float sq = v.x * v.x + v.y * v.y + v.z * v.z + v.w * v.w;
#pragma unroll
  for (int off = 32; off > 0; off >>= 1) {
    s  += __shfl_xor(s, off);
    sq += __shfl_xor(sq, off);
  }
  if ((tid & 63) == 0) { red[tid >> 6] = s; red[4 + (tid >> 6)] = sq; }
  __syncthreads();
  const float ts = red[0] + red[1] + red[2] + red[3];
  const float tq = red[4] + red[5] + red[6] + red[7];
  const float mean = ts * (1.0f / DM);
  const float var  = tq * (1.0f / DM) - mean * mean;
  const float rstd = rsqrtf(var + 1e-5f);
  const float4 gv = *(const float4*)&g[c];
  const float4 bv = *(const float4*)&b[c];
  const float o0 = (v.x - mean) * rstd * gv.x + bv.x;
  const float o1 = (v.y - mean) * rstd * gv.y + bv.y;
  const float o2 = (v.z - mean) * rstd * gv.z + bv.z;
  const float o3 = (v.w - mean) * rstd * gv.w + bv.w;
  if constexpr (OUTBF) {
    bf16x4v ov = {(bf16)o0, (bf16)o1, (bf16)o2, (bf16)o3};
    *(bf16x4v*)&outB[(size_t)row * DM + c] = ov;
  } else {
    *(float4*)&outF[(size_t)row * DM + c] = make_float4(o0, o1, o2, o3);
  }
}

// ---------------- weight transpose+convert: W[K,N] f32 -> Wt[N,K] bf16 ----------------
__global__ __launch_bounds__(256) void wtrans_kernel(
    const float* __restrict__ W, bf16* __restrict__ Wt, int N, int K)
{
  __shared__ __attribute__((aligned(16))) bf16 T[64][72];  // +8 pad
  const int tid = threadIdx.x;
  const int n0 = blockIdx.x * 64;
  const int k0 = blockIdx.y * 64;
#pragma unroll
  for (int p = 0; p < 4; ++p) {
    const int flat = p * 1024 + tid * 4;
    const int kr = flat >> 6;          // 0..63
    const int nc = flat & 63;          // multiple of 4
    const float4 v = *(const float4*)&W[(size_t)(k0 + kr) * N + n0 + nc];
    T[nc + 0][kr] = (bf16)v.x;
    T[nc + 1][kr] = (bf16)v.y;
    T[nc + 2][kr] = (bf16)v.z;
    T[nc + 3][kr] = (bf16)v.w;
  }
  __syncthreads();
#pragma unroll
  for (int p = 0; p < 2; ++p) {
    const int flat = p * 2048 + tid * 8;
    const int nr = flat >> 6;          // 0..63
    const int kc = flat & 63;          // multiple of 8
    const bf16x8 v = *(const bf16x8*)&T[nr][kc];
    *(bf16x8*)&Wt[(size_t)(n0 + nr) * K + k0 + kc] = v;
  }
}

// ---------------- concat q/kv biases: bqkv[l][3072] ----------------
__global__ __launch_bounds__(256) void bias_concat_kernel(
    const float* __restrict__ bq, const float* __restrict__ bkv,
    float* __restrict__ bqkv)
{
  const int i = blockIdx.x * 256 + threadIdx.x;   // 6*3072
  const int l = i / 3072, j = i - l * 3072;
  bqkv[i] = (j < 1024) ? bq[l * 1024 + j] : bkv[l * 2048 + (j - 1024)];
}

// ---------------- GEMM (m97 structure): C[M,N] = A[M,K] @ Bt[N,K]^T ----------------
// 128x128 tile, BK=32, 256 threads = 4 waves (2x2), acc[4][4] per wave.
// XCD-aware swizzle (T1) keeps co-resident blocks' panels in one XCD's L2.
// SPLITK: gridDim.z splits the K range; each split writes an f32 partial
// slice at z*M*N (no bias/resid/relu) -- reduced later in red_ln_kernel.
template<bool RELU, bool RESID, bool OUTBF, bool SPLITK>
__global__ __launch_bounds__(256) void gemm128(
    const bf16* __restrict__ A, const bf16* __restrict__ Bt,
    const float* __restrict__ bias, const float* __restrict__ resid,
    bf16* __restrict__ outB, float* __restrict__ outF,
    int M, int N, int K)
{
  __shared__ __attribute__((aligned(16))) bf16 As[128][32];
  __shared__ __attribute__((aligned(16))) bf16 Bs[128][32];
  const int tid  = threadIdx.x;
  const int lane = tid & 63;
  const int w    = tid >> 6;
  const int quad = lane >> 4;
  const int l16  = lane & 15;
  const int wr = w >> 1, wc = w & 1;

  // ---- XCD swizzle (per z-slice; nwg % 8 == 0 for all launches) ----
  const int gx    = gridDim.x;
  const int nwg   = gx * gridDim.y;
  const int orig  = blockIdx.y * gx + blockIdx.x;
  const int chunk = nwg >> 3;
  const int nl    = (orig & 7) * chunk + (orig >> 3);
  const int m0 = (nl / gx) * 128;
  const int n0 = (nl % gx) * 128;

  const int kspan = K / (int)gridDim.z;
  const int kbeg  = blockIdx.z * kspan;

  f32x4 acc[4][4] = {};

  // staging addresses: flat slot tid (+256) covers [row= flat>>2][kcol=(flat&3)*8]
  const int r0 = tid >> 2;
  const int kg = (tid & 3) << 3;
  const bf16* a0 = &A [(size_t)(m0 + r0)      * K + kg];
  const bf16* a1 = &A [(size_t)(m0 + 64 + r0) * K + kg];
  const bf16* b0 = &Bt[(size_t)(n0 + r0)      * K + kg];
  const bf16* b1 = &Bt[(size_t)(n0 + 64 + r0) * K + kg];
  bf16* asd0 = &As[0][0] + (size_t)tid * 8;
  bf16* asd1 = &As[0][0] + (size_t)(256 + tid) * 8;
  bf16* bsd0 = &Bs[0][0] + (size_t)tid * 8;
  bf16* bsd1 = &Bs[0][0] + (size_t)(256 + tid) * 8;

  for (int k0 = kbeg; k0 < kbeg + kspan; k0 += 32) {
    __syncthreads();
    __builtin_amdgcn_global_load_lds((gp_t)(a0 + k0), (lp_t)asd0, 16, 0, 0);
    __builtin_amdgcn_global_load_lds((gp_t)(a1 + k0), (lp_t)asd1, 16, 0, 0);
    __builtin_amdgcn_global_load_lds((gp_t)(b0 + k0), (lp_t)bsd0, 16, 0, 0);
    __builtin_amdgcn_global_load_lds((gp_t)(b1 + k0), (lp_t)bsd1, 16, 0, 0);
    __syncthreads();

    bf16x8 af[4], bfg[4];
#pragma unroll
    for (int mt = 0; mt < 4; ++mt)
      af[mt] = *(const bf16x8*)&As[(wr << 6) + (mt << 4) + l16][quad << 3];
#pragma unroll
    for (int nt = 0; nt < 4; ++nt)
      bfg[nt] = *(const bf16x8*)&Bs[(wc << 6) + (nt << 4) + l16][quad << 3];
#pragma unroll
    for (int mt = 0; mt < 4; ++mt)
#pragma unroll
      for (int nt = 0; nt < 4; ++nt)
        acc[mt][nt] = __builtin_amdgcn_mfma_f32_16x16x32_bf16(af[mt], bfg[nt], acc[mt][nt], 0, 0, 0);
  }

  // epilogue: C/D layout col=lane&15, row=quad*4+r
  const int rbase = quad << 2;
  const size_t zoff = (size_t)blockIdx.z * M * N;
#pragma unroll
  for (int nt = 0; nt < 4; ++nt) {
    const int col = n0 + (wc << 6) + (nt << 4) + l16;
    const float bb = SPLITK ? 0.0f : bias[col];
#pragma unroll
    for (int mt = 0; mt < 4; ++mt) {
#pragma unroll
      for (int r = 0; r < 4; ++r) {
        const int row = m0 + (wr << 6) + (mt << 4) + rbase + r;
        float val = acc[mt][nt][r] + bb;
        if constexpr (SPLITK) {
          outF[zoff + (size_t)row * N + col] = val;
        } else {
          if constexpr (RESID) val += resid[(size_t)row * N + col];
          if constexpr (RELU)  val = fmaxf(val, 0.f);
          if constexpr (OUTBF) outB[(size_t)row * N + col] = (bf16)val;
          else                 outF[(size_t)row * N + col] = val;
        }
      }
    }
  }
}

// ---------------- fused flash attention (packed qkv [4096][3072]) ----------------
// grid: (S/64 q-tiles, H, B); block 256 = 4 waves; wave w owns q rows 16w..16w+15.
// Round-4 changes vs round-3:
//  (a) V staged with COALESCED vector loads into row-major Vs, then transposed
//      inside LDS (was: 4096 uncoalesced scalar global loads per tile).
//  (b) XOR swizzle (elem col ^= (row&7)<<3, i.e. byte ^= (row&7)<<4) on
//      Qs/Ks/Vt/Ps: the [*][64] bf16 layout has 128B row stride, so the 16
//      l16-lanes of every fragment read hit one bank set (16-way conflict).
//      Swizzle spreads them across all banks (guide G4 / attn-ladder +89%).
__global__ __launch_bounds__(256) void attn_kernel(
    const bf16* __restrict__ qkv, const int* __restrict__ lengths,
    bf16* __restrict__ o)
{
  __shared__ __attribute__((aligned(16))) bf16 Qs[64][64];     // [q][d]   swz
  __shared__ __attribute__((aligned(16))) bf16 Ks[64][64];     // [kk][d]  swz
  __shared__ __attribute__((aligned(16))) bf16 Vs[64][64];     // [kk][dv] linear
  __shared__ __attribute__((aligned(16))) bf16 Vt[64][64];     // [dv][kk] swz
  __shared__ __attribute__((aligned(16))) bf16 Ps[4][16][64];  // per-wave P, swz

  const int tid  = threadIdx.x;
  const int lane = tid & 63;
  const int w    = tid >> 6;
  const int quad = lane >> 4;
  const int l16  = lane & 15;
  const int qt = blockIdx.x, hh = blockIdx.y, b = blockIdx.z;
  const int q0 = qt * 64;
  const int len = lengths[b];
  const float scale = 0.125f;  // 1/sqrt(64)

  // stage Q tile once (swizzled)
#pragma unroll
  for (int r = 0; r < 2; ++r) {
    const int slot = tid + 256 * r;
    const int row = slot >> 3, dg = (slot & 7) << 3;
    *(bf16x8*)&Qs[row][dg ^ ((row & 7) << 3)] =
        *(const bf16x8*)&qkv[(size_t)(b * SB + q0 + row) * 3072 + hh * 64 + dg];
  }

  f32x4 Oacc[4] = {};
  float m_i[4] = {-1e30f, -1e30f, -1e30f, -1e30f};
  float l_i[4] = {0.f, 0.f, 0.f, 0.f};

  for (int kt0 = 0; kt0 < SB; kt0 += 64) {
    if (kt0 >= len) break;   // block-uniform
    __syncthreads();
    // stage K tile [kk][d] (swizzled) and V tile [kk][dv] (linear), coalesced
#pragma unroll
    for (int r = 0; r < 2; ++r) {
      const int slot = tid + 256 * r;
      const int row = slot >> 3, dg = (slot & 7) << 3;
      const size_t gbase = (size_t)(b * SB + kt0 + row) * 3072 + hh * 64 + dg;
      *(bf16x8*)&Ks[row][dg ^ ((row & 7) << 3)] =
          *(const bf16x8*)&qkv[gbase + 1024];
      *(bf16x8*)&Vs[row][dg] =
          *(const bf16x8*)&qkv[gbase + 2048];
    }
    __syncthreads();

    // S tile = Q @ K^T
    f32x4 s[4] = {};
    const int qrow = (w << 4) + l16;
#pragma unroll
    for (int ds = 0; ds < 2; ++ds) {
      const int cbase = (ds << 5) + (quad << 3);
      const bf16x8 af = *(const bf16x8*)&Qs[qrow][cbase ^ ((qrow & 7) << 3)];
#pragma unroll
      for (int nt = 0; nt < 4; ++nt) {
        const int krow = (nt << 4) + l16;
        const bf16x8 bfr = *(const bf16x8*)&Ks[krow][cbase ^ ((krow & 7) << 3)];
        s[nt] = __builtin_amdgcn_mfma_f32_16x16x32_bf16(af, bfr, s[nt], 0, 0, 0);
      }
    }
    // scale + key mask
#pragma unroll
    for (int nt = 0; nt < 4; ++nt) {
      const bool valid = (kt0 + (nt << 4) + l16) < len;
#pragma unroll
      for (int r = 0; r < 4; ++r)
        s[nt][r] = valid ? s[nt][r] * scale : -1e30f;
    }
    // row max
    float mt[4];
#pragma unroll
    for (int r = 0; r < 4; ++r)
      mt[r] = fmaxf(fmaxf(s[0][r], s[1][r]), fmaxf(s[2][r], s[3][r]));
#pragma unroll
    for (int off = 1; off < 16; off <<= 1)
#pragma unroll
      for (int r = 0; r < 4; ++r)
        mt[r] = fmaxf(mt[r], __shfl_xor(mt[r], off));
    float alpha[4];
#pragma unroll
    for (int r = 0; r < 4; ++r) {
      const float mn = fmaxf(m_i[r], mt[r]);
      alpha[r] = __expf(m_i[r] - mn);
      m_i[r] = mn;
    }
    // exponentiate + row sums
    float rs[4] = {0.f, 0.f, 0.f, 0.f};
#pragma unroll
    for (int nt = 0; nt < 4; ++nt)
#pragma unroll
      for (int r = 0; r < 4; ++r) {
        const float pe = __expf(s[nt][r] - m_i[r]);
        s[nt][r] = pe;
        rs[r] += pe;
      }
#pragma unroll
    for (int off = 1; off < 16; off <<= 1)
#pragma unroll
      for (int r = 0; r < 4; ++r)
        rs[r] += __shfl_xor(rs[r], off);
#pragma unroll
    for (int r = 0; r < 4; ++r) l_i[r] = l_i[r] * alpha[r] + rs[r];
    // P (C-layout) -> LDS (A-layout, swizzled), rescale O
#pragma unroll
    for (int nt = 0; nt < 4; ++nt)
#pragma unroll
      for (int r = 0; r < 4; ++r) {
        const int prow = (quad << 2) + r;
        Ps[w][prow][((nt << 4) + l16) ^ ((prow & 7) << 3)] = (bf16)s[nt][r];
        Oacc[nt][r] *= alpha[r];
      }
    // transpose Vs[kk][dv] -> Vt[dv][kk] (swizzled), all inside LDS
#pragma unroll
    for (int r2 = 0; r2 < 2; ++r2) {
      const int dv = tid & 63;
      const int kg2 = ((tid >> 6) << 3) + (r2 << 5);
      bf16x8 vv;
#pragma unroll
      for (int u = 0; u < 8; ++u)
        vv[u] = Vs[kg2 + u][dv];
      *(bf16x8*)&Vt[dv][kg2 ^ ((dv & 7) << 3)] = vv;
    }
    __syncthreads();
    // O += P @ V
#pragma unroll
    for (int ks = 0; ks < 2; ++ks) {
      const int cbase = (ks << 5) + (quad << 3);
      const bf16x8 af = *(const bf16x8*)&Ps[w][l16][cbase ^ ((l16 & 7) << 3)];
#pragma unroll
      for (int nt = 0; nt < 4; ++nt) {
        const int vrow = (nt << 4) + l16;
        const bf16x8 bfr = *(const bf16x8*)&Vt[vrow][cbase ^ ((vrow & 7) << 3)];
        Oacc[nt] = __builtin_amdgcn_mfma_f32_16x16x32_bf16(af, bfr, Oacc[nt], 0, 0, 0);
      }
    }
  }
  // epilogue
  float inv[4];
#pragma unroll
  for (int r = 0; r < 4; ++r) inv[r] = 1.0f / l_i[r];
#pragma unroll
  for (int nt = 0; nt < 4; ++nt)
#pragma unroll
    for (int r = 0; r < 4; ++r) {
      const int row = b * SB + q0 + (w << 4) + (quad << 2) + r;
      const int col = hh * 64 + (nt << 4) + l16;
      o[(size_t)row * 1024 + col] = (bf16)(Oacc[nt][r] * inv[r]);
    }
}

extern "C" void kernel_launch(void* const* d_in, const int* in_sizes, int n_in,
                              void* d_out, int out_size, void* d_ws, size_t ws_size,
                              hipStream_t stream) {
  const int*   tokens = (const int*)  d_in[0];
  const int*   lengths= (const int*)  d_in[1];
  const float* emb    = (const float*)d_in[2];
  const float* Wq     = (const float*)d_in[3];
  const float* bq     = (const float*)d_in[4];
  const float* Wkv    = (const float*)d_in[5];
  const float* bkv    = (const float*)d_in[6];
  const float* Wo     = (const float*)d_in[7];
  const float* bo     = (const float*)d_in[8];
  const float* lag    = (const float*)d_in[9];
  const float* lab    = (const float*)d_in[10];
  const float* W1     = (const float*)d_in[11];
  const float* b1     = (const float*)d_in[12];
  const float* W2     = (const float*)d_in[13];
  const float* b2     = (const float*)d_in[14];
  const float* lfg    = (const float*)d_in[15];  // ln_ffn_g
  const float* lfb    = (const float*)d_in[16];  // ln_ffn_b
  const float* lgf    = (const float*)d_in[17];  // ln_f_g
  const float* lbf    = (const float*)d_in[18];  // ln_f_b

  char* p = (char*)d_ws;
  float* x     = (float*)p; p += (size_t)4096 * 1024 * 4;   // residual f32 (16MB)
  bf16*  h     = (bf16*)p;  p += (size_t)4096 * 1024 * 2;   // LN out (8MB)
  bf16*  qkv   = (bf16*)p;  p += (size_t)4096 * 3072 * 2;   // fused QKV (24MB)
  bf16*  o     = (bf16*)p;  p += (size_t)4096 * 1024 * 2;   // attn out (8MB)
  bf16*  mid   = (bf16*)p;  p += (size_t)4096 * 4096 * 2;   // FFN mid (32MB)
  bf16*  wqkvt = (bf16*)p;  p += (size_t)3072 * 1024 * 2;   // Wqkv^T (6MB)
  bf16*  wot   = (bf16*)p;  p += (size_t)1024 * 1024 * 2;   // Wo^T (2MB)
  bf16*  w1t   = (bf16*)p;  p += (size_t)4096 * 1024 * 2;   // W1^T (8MB)
  bf16*  w2t   = (bf16*)p;  p += (size_t)1024 * 4096 * 2;   // W2^T (8MB)
  float* bqkv  = (float*)p; p += (size_t)6 * 3072 * 4;      // concat bias
  p = (char*)(((size_t)p + 255) & ~(size_t)255);
  float* part  = (float*)p; p += (size_t)4 * 4096 * 1024 * 4; // split-K partials (64MB)

  bias_concat_kernel<<<72, 256, 0, stream>>>(bq, bkv, bqkv);
  embed_kernel<<<4096, 256, 0, stream>>>(tokens, emb, x);

  for (int l = 0; l < 6; ++l) {
    // per-layer weight transpose+convert (bf16, [N][K])
    wtrans_kernel<<<dim3(16, 16), 256, 0, stream>>>(
        Wq + (size_t)l * 1024 * 1024, wqkvt, 1024, 1024);
    wtrans_kernel<<<dim3(32, 16), 256, 0, stream>>>(
        Wkv + (size_t)l * 1024 * 2048, wqkvt + (size_t)1024 * 1024, 2048, 1024);
    wtrans_kernel<<<dim3(16, 16), 256, 0, stream>>>(
        Wo + (size_t)l * 1024 * 1024, wot, 1024, 1024);
    wtrans_kernel<<<dim3(64, 16), 256, 0, stream>>>(
        W1 + (size_t)l * 1024 * 4096, w1t, 4096, 1024);
    wtrans_kernel<<<dim3(16, 64), 256, 0, stream>>>(
        W2 + (size_t)l * 4096 * 1024, w2t, 1024, 4096);

    // --- attn sublayer ---
    if (l == 0) {
      ln_kernel<true><<<4096, 256, 0, stream>>>(
          x, lag, lab, h, nullptr);
    } else {
      // reduce previous layer's W2 partials (+b2_{l-1}) into x, then ln_attn
      red_ln_kernel<4, true, true><<<4096, 256, 0, stream>>>(
          x, part, b2 + (size_t)(l - 1) * 1024,
          lag + (size_t)l * 1024, lab + (size_t)l * 1024, x, h, nullptr);
    }
    gemm128<false, false, true, false><<<dim3(24, 32), 256, 0, stream>>>(
        h, wqkvt, bqkv + (size_t)l * 3072, nullptr, qkv, nullptr, 4096, 3072, 1024);
    attn_kernel<<<dim3(8, 16, 8), 256, 0, stream>>>(qkv, lengths, o);
    // attn-out projection, split-K=2 -> partials (grid 512 = 2 blocks/CU)
    gemm128<false, false, false, true><<<dim3(8, 32, 2), 256, 0, stream>>>(
        o, wot, nullptr, nullptr, nullptr, part, 4096, 1024, 1024);
    // --- FFN sublayer ---
    // reduce Wo partials (+bo) into x, then ln_ffn
    red_ln_kernel<2, true, true><<<4096, 256, 0, stream>>>(
        x, part, bo + (size_t)l * 1024,
        lfg + (size_t)l * 1024, lfb + (size_t)l * 1024, x, h, nullptr);
    gemm128<true, false, true, false><<<dim3(32, 32), 256, 0, stream>>>(
        h, w1t, b1 + (size_t)l * 4096, nullptr, mid, nullptr, 4096, 4096, 1024);
    // FFN down projection, split-K=4 -> partials (grid 1024 = 4 blocks/CU)
    gemm128<false, false, false, true><<<dim3(8, 32, 4), 256, 0, stream>>>(
        mid, w2t, nullptr, nullptr, nullptr, part, 4096, 1024, 4096);
  }
  // final: reduce layer-5 W2 partials (+b2_5) and apply ln_f -> d_out (f32)
  red_ln_kernel<4, false, false><<<4096, 256, 0, stream>>>(
      x, part, b2 + (size_t)5 * 1024, lgf, lbf, nullptr, nullptr, (float*)d_out);
}

// Round 6
// 1607.326 us; speedup vs baseline: 1.3574x; 1.1774x over previous
//
#include <hip/hip_runtime.h>
#include <hip/hip_bf16.h>
#include <math.h>

typedef __bf16 bf16;
typedef bf16 bf16x8 __attribute__((ext_vector_type(8)));
typedef bf16 bf16x4v __attribute__((ext_vector_type(4)));
typedef float f32x4 __attribute__((ext_vector_type(4)));

typedef const __attribute__((address_space(1))) void* gp_t;
typedef __attribute__((address_space(3))) void* lp_t;

#define SB 512
#define DM 1024

// ---------------- embedding + sinusoidal PE ----------------
__global__ __launch_bounds__(256) void embed_kernel(
    const int* __restrict__ tokens, const float* __restrict__ emb,
    float* __restrict__ x)
{
  const int row = blockIdx.x;              // b*S + s
  const int s = row & (SB - 1);
  const int tok = tokens[row];
  const int c = threadIdx.x * 4;
  const float4 e = *(const float4*)&emb[(size_t)tok * DM + c];
  const float ev[4] = {e.x, e.y, e.z, e.w};
  float o[4];
#pragma unroll
  for (int u = 0; u < 4; ++u) {
    int i = c + u;
    int j = i & ~1;
    float freq = __expf(-9.210340371976184f * (float)j * (1.0f / (float)DM));
    float ang = (float)s * freq;
    float pe = ((i & 1) == 0) ? __sinf(ang) : __cosf(ang);
    o[u] = ev[u] * 32.0f + pe;             // sqrt(1024) = 32
  }
  *(float4*)&x[(size_t)row * DM + c] = make_float4(o[0], o[1], o[2], o[3]);
}

// ---------------- layernorm (one block per row, D=1024) ----------------
template<bool OUTBF>
__global__ __launch_bounds__(256) void ln_kernel(
    const float* __restrict__ x, const float* __restrict__ g,
    const float* __restrict__ b, bf16* __restrict__ outB,
    float* __restrict__ outF)
{
  __shared__ float red[8];
  const int row = blockIdx.x, tid = threadIdx.x;
  const float4 v = *(const float4*)&x[(size_t)row * DM + tid * 4];
  float s = v.x + v.y + v.z + v.w;
  float sq = v.x * v.x + v.y * v.y + v.z * v.z + v.w * v.w;
#pragma unroll
  for (int off = 32; off > 0; off >>= 1) {
    s  += __shfl_xor(s, off);
    sq += __shfl_xor(sq, off);
  }
  if ((tid & 63) == 0) { red[tid >> 6] = s; red[4 + (tid >> 6)] = sq; }
  __syncthreads();
  const float ts = red[0] + red[1] + red[2] + red[3];
  const float tq = red[4] + red[5] + red[6] + red[7];
  const float mean = ts * (1.0f / DM);
  const float var  = tq * (1.0f / DM) - mean * mean;
  const float rstd = rsqrtf(var + 1e-5f);
  const int c = tid * 4;
  const float4 gv = *(const float4*)&g[c];
  const float4 bv = *(const float4*)&b[c];
  const float o0 = (v.x - mean) * rstd * gv.x + bv.x;
  const float o1 = (v.y - mean) * rstd * gv.y + bv.y;
  const float o2 = (v.z - mean) * rstd * gv.z + bv.z;
  const float o3 = (v.w - mean) * rstd * gv.w + bv.w;
  if constexpr (OUTBF) {
    bf16x4v ov = {(bf16)o0, (bf16)o1, (bf16)o2, (bf16)o3};
    *(bf16x4v*)&outB[(size_t)row * DM + c] = ov;
  } else {
    *(float4*)&outF[(size_t)row * DM + c] = make_float4(o0, o1, o2, o3);
  }
}

// ---------------- fused split-K reduce + residual + bias + layernorm ----------------
template<int NS, bool OUTBF, bool WRITEX>
__global__ __launch_bounds__(256) void red_ln_kernel(
    const float* __restrict__ x, const float* __restrict__ part,
    const float* __restrict__ badd, const float* __restrict__ g,
    const float* __restrict__ b, float* __restrict__ xout,
    bf16* __restrict__ outB, float* __restrict__ outF)
{
  __shared__ float red[8];
  const int row = blockIdx.x, tid = threadIdx.x;
  const int c = tid * 4;
  const size_t base = (size_t)row * DM + c;
  float4 v = *(const float4*)&x[base];
  const float4 ba = *(const float4*)&badd[c];
  v.x += ba.x; v.y += ba.y; v.z += ba.z; v.w += ba.w;
#pragma unroll
  for (int z = 0; z < NS; ++z) {
    const float4 pv = *(const float4*)&part[(size_t)z * 4096 * DM + base];
    v.x += pv.x; v.y += pv.y; v.z += pv.z; v.w += pv.w;
  }
  if constexpr (WRITEX) *(float4*)&xout[base] = v;
  float s = v.x + v.y + v.z + v.w;
  float sq = v.x * v.x + v.y * v.y + v.z * v.z + v.w * v.w;
#pragma unroll
  for (int off = 32; off > 0; off >>= 1) {
    s  += __shfl_xor(s, off);
    sq += __shfl_xor(sq, off);
  }
  if ((tid & 63) == 0) { red[tid >> 6] = s; red[4 + (tid >> 6)] = sq; }
  __syncthreads();
  const float ts = red[0] + red[1] + red[2] + red[3];
  const float tq = red[4] + red[5] + red[6] + red[7];
  const float mean = ts * (1.0f / DM);
  const float var  = tq * (1.0f / DM) - mean * mean;
  const float rstd = rsqrtf(var + 1e-5f);
  const float4 gv = *(const float4*)&g[c];
  const float4 bv = *(const float4*)&b[c];
  const float o0 = (v.x - mean) * rstd * gv.x + bv.x;
  const float o1 = (v.y - mean) * rstd * gv.y + bv.y;
  const float o2 = (v.z - mean) * rstd * gv.z + bv.z;
  const float o3 = (v.w - mean) * rstd * gv.w + bv.w;
  if constexpr (OUTBF) {
    bf16x4v ov = {(bf16)o0, (bf16)o1, (bf16)o2, (bf16)o3};
    *(bf16x4v*)&outB[(size_t)row * DM + c] = ov;
  } else {
    *(float4*)&outF[(size_t)row * DM + c] = make_float4(o0, o1, o2, o3);
  }
}

// ---------------- weight transpose+convert: W[K,N] f32 -> Wt[N,K] bf16 ----------------
__global__ __launch_bounds__(256) void wtrans_kernel(
    const float* __restrict__ W, bf16* __restrict__ Wt, int N, int K)
{
  __shared__ __attribute__((aligned(16))) bf16 T[64][72];  // +8 pad
  const int tid = threadIdx.x;
  const int n0 = blockIdx.x * 64;
  const int k0 = blockIdx.y * 64;
#pragma unroll
  for (int p = 0; p < 4; ++p) {
    const int flat = p * 1024 + tid * 4;
    const int kr = flat >> 6;          // 0..63
    const int nc = flat & 63;          // multiple of 4
    const float4 v = *(const float4*)&W[(size_t)(k0 + kr) * N + n0 + nc];
    T[nc + 0][kr] = (bf16)v.x;
    T[nc + 1][kr] = (bf16)v.y;
    T[nc + 2][kr] = (bf16)v.z;
    T[nc + 3][kr] = (bf16)v.w;
  }
  __syncthreads();
#pragma unroll
  for (int p = 0; p < 2; ++p) {
    const int flat = p * 2048 + tid * 8;
    const int nr = flat >> 6;          // 0..63
    const int kc = flat & 63;          // multiple of 8
    const bf16x8 v = *(const bf16x8*)&T[nr][kc];
    *(bf16x8*)&Wt[(size_t)(n0 + nr) * K + k0 + kc] = v;
  }
}

// ---------------- concat q/kv biases: bqkv[l][3072] ----------------
__global__ __launch_bounds__(256) void bias_concat_kernel(
    const float* __restrict__ bq, const float* __restrict__ bkv,
    float* __restrict__ bqkv)
{
  const int i = blockIdx.x * 256 + threadIdx.x;   // 6*3072
  const int l = i / 3072, j = i - l * 3072;
  bqkv[i] = (j < 1024) ? bq[l * 1024 + j] : bkv[l * 2048 + (j - 1024)];
}

// ---------------- GEMM 256x256, BK=64, 8 waves (2x4), dbuf LDS, T2 swizzle ----------
// C[M,N] = A[M,K] @ Bt[N,K]^T.  512 threads; wave (wm,wn) owns a 128x64 output.
// Pipeline (T3 minimum 2-phase, race-free): per K-tile, issue the 8
// global_load_lds for tile t+1 into buf[cur^1] FIRST, then ds_read+MFMA tile t
// from buf[cur], then one __syncthreads() (drains vmcnt+lgkm) and swap.
// LDS layout [row][64] bf16 is a 16-way bank conflict on fragment reads;
// T2 swizzle byte ^= (row&7)<<4, applied BOTH sides (rule #21): staging
// pre-swizzles the global source (LDS dest stays linear, as global_load_lds
// requires), reads XOR the same involution.
// SPLITK: gridDim.z splits K; z-slice writes f32 partials at z*M*N.
template<bool RELU, bool OUTBF, bool SPLITK>
__global__ __launch_bounds__(512, 2) void gemm256(
    const bf16* __restrict__ A, const bf16* __restrict__ Bt,
    const float* __restrict__ bias,
    bf16* __restrict__ outB, float* __restrict__ outF,
    int M, int N, int K)
{
  __shared__ __attribute__((aligned(16))) bf16 sm[2][2][256 * 64];  // 128 KiB

  const int tid  = threadIdx.x;
  const int lane = tid & 63;
  const int w    = tid >> 6;        // 0..7
  const int quad = lane >> 4;       // 0..3
  const int l16  = lane & 15;
  const int wm   = w >> 2;          // 0..1  (M half)
  const int wn   = w & 3;           // 0..3  (N quarter)

  // ---- XCD swizzle (per z-slice; nwg % 8 == 0 for all launches) ----
  const int gx    = gridDim.x;
  const int nwg   = gx * gridDim.y;
  const int orig  = blockIdx.y * gx + blockIdx.x;
  const int chunk = nwg >> 3;
  const int nl    = (orig & 7) * chunk + (orig >> 3);
  const int m0 = (nl / gx) * 256;
  const int n0 = (nl % gx) * 256;

  const int kspan = K / (int)gridDim.z;
  const int kbeg  = blockIdx.z * kspan;
  const int ntile = kspan >> 6;

  // staging: thread t covers linear LDS elems t*8 + i*4096 (i=0..3) per operand.
  // linear elem L -> row = L>>6, physical slot s=(L>>3)&7 holds global slot
  // s ^ (row&7) (pre-swizzled source; LDS dest linear as gload_lds requires).
  const int rowst = tid >> 3;                        // 0..63 (+64 per i)
  const int slot  = (tid & 7) ^ (rowst & 7);         // pre-swizzled 8-elem slot
  const int colst = slot << 3;
  const bf16* aSrc = A  + (size_t)(m0 + rowst) * K + kbeg + colst;
  const bf16* bSrc = Bt + (size_t)(n0 + rowst) * K + kbeg + colst;

  f32x4 acc[8][4] = {};
  const int xm = (l16 & 7) << 3;   // read-side swizzle mask (row&7 == l16&7)

#define STAGE256(buf, koff) do {                                           \
    const bf16* as_ = aSrc + (koff);                                       \
    const bf16* bs_ = bSrc + (koff);                                       \
    bf16* ad_ = &sm[buf][0][tid * 8];                                      \
    bf16* bd_ = &sm[buf][1][tid * 8];                                      \
    _Pragma("unroll")                                                      \
    for (int i_ = 0; i_ < 4; ++i_) {                                       \
      __builtin_amdgcn_global_load_lds((gp_t)(as_ + (size_t)i_ * 64 * K),  \
                                       (lp_t)(ad_ + i_ * 4096), 16, 0, 0); \
      __builtin_amdgcn_global_load_lds((gp_t)(bs_ + (size_t)i_ * 64 * K),  \
                                       (lp_t)(bd_ + i_ * 4096), 16, 0, 0); \
    }                                                                      \
  } while (0)

  STAGE256(0, 0);
  __syncthreads();

  int cur = 0;
  for (int t = 0; t < ntile; ++t) {
    if (t + 1 < ntile) STAGE256(cur ^ 1, (t + 1) << 6);   // issue-early

    const bf16* Ab = &sm[cur][0][0];
    const bf16* Bb = &sm[cur][1][0];

    bf16x8 bF[4][2];
#pragma unroll
    for (int nt = 0; nt < 4; ++nt)
#pragma unroll
      for (int ks = 0; ks < 2; ++ks) {
        const int rowb = (wn << 6) + (nt << 4) + l16;
        bF[nt][ks] = *(const bf16x8*)&Bb[rowb * 64 + (((ks << 5) + (quad << 3)) ^ xm)];
      }
#pragma unroll
    for (int p = 0; p < 4; ++p) {
      bf16x8 aF[2][2];
#pragma unroll
      for (int m2 = 0; m2 < 2; ++m2)
#pragma unroll
        for (int ks = 0; ks < 2; ++ks) {
          const int rowa = (wm << 7) + (((p << 1) + m2) << 4) + l16;
          aF[m2][ks] = *(const bf16x8*)&Ab[rowa * 64 + (((ks << 5) + (quad << 3)) ^ xm)];
        }
      __builtin_amdgcn_s_setprio(1);
#pragma unroll
      for (int m2 = 0; m2 < 2; ++m2)
#pragma unroll
        for (int nt = 0; nt < 4; ++nt)
#pragma unroll
          for (int ks = 0; ks < 2; ++ks)
            acc[(p << 1) + m2][nt] = __builtin_amdgcn_mfma_f32_16x16x32_bf16(
                aF[m2][ks], bF[nt][ks], acc[(p << 1) + m2][nt], 0, 0, 0);
      __builtin_amdgcn_s_setprio(0);
    }
    __syncthreads();   // drains vmcnt (t+1 staged) + lgkm; protects buf swap
    cur ^= 1;
  }

  // epilogue: C/D layout col=lane&15, row=quad*4+r
  const int rb = quad << 2;
#pragma unroll
  for (int mt = 0; mt < 8; ++mt) {
#pragma unroll
    for (int nt = 0; nt < 4; ++nt) {
      const int col  = n0 + (wn << 6) + (nt << 4) + l16;
      const int rowg = m0 + (wm << 7) + (mt << 4) + rb;
      if constexpr (SPLITK) {
        float* dst = outF + (size_t)blockIdx.z * M * N + (size_t)rowg * N + col;
#pragma unroll
        for (int r = 0; r < 4; ++r) dst[(size_t)r * N] = acc[mt][nt][r];
      } else {
        const float bb = bias[col];
#pragma unroll
        for (int r = 0; r < 4; ++r) {
          float v = acc[mt][nt][r] + bb;
          if constexpr (RELU) v = fmaxf(v, 0.f);
          if constexpr (OUTBF) outB[(size_t)(rowg + r) * N + col] = (bf16)v;
          else                 outF[(size_t)(rowg + r) * N + col] = v;
        }
      }
    }
  }
#undef STAGE256
}

// ---------------- fused flash attention (packed qkv [4096][3072]) ----------------
__global__ __launch_bounds__(256) void attn_kernel(
    const bf16* __restrict__ qkv, const int* __restrict__ lengths,
    bf16* __restrict__ o)
{
  __shared__ __attribute__((aligned(16))) bf16 Qs[64][64];     // [q][d]   swz
  __shared__ __attribute__((aligned(16))) bf16 Ks[64][64];     // [kk][d]  swz
  __shared__ __attribute__((aligned(16))) bf16 Vs[64][64];     // [kk][dv] linear
  __shared__ __attribute__((aligned(16))) bf16 Vt[64][64];     // [dv][kk] swz
  __shared__ __attribute__((aligned(16))) bf16 Ps[4][16][64];  // per-wave P, swz

  const int tid  = threadIdx.x;
  const int lane = tid & 63;
  const int w    = tid >> 6;
  const int quad = lane >> 4;
  const int l16  = lane & 15;
  const int qt = blockIdx.x, hh = blockIdx.y, b = blockIdx.z;
  const int q0 = qt * 64;
  const int len = lengths[b];
  const float scale = 0.125f;  // 1/sqrt(64)

  // stage Q tile once (swizzled)
#pragma unroll
  for (int r = 0; r < 2; ++r) {
    const int slot = tid + 256 * r;
    const int row = slot >> 3, dg = (slot & 7) << 3;
    *(bf16x8*)&Qs[row][dg ^ ((row & 7) << 3)] =
        *(const bf16x8*)&qkv[(size_t)(b * SB + q0 + row) * 3072 + hh * 64 + dg];
  }

  f32x4 Oacc[4] = {};
  float m_i[4] = {-1e30f, -1e30f, -1e30f, -1e30f};
  float l_i[4] = {0.f, 0.f, 0.f, 0.f};

  for (int kt0 = 0; kt0 < SB; kt0 += 64) {
    if (kt0 >= len) break;   // block-uniform
    __syncthreads();
    // stage K tile [kk][d] (swizzled) and V tile [kk][dv] (linear), coalesced
#pragma unroll
    for (int r = 0; r < 2; ++r) {
      const int slot = tid + 256 * r;
      const int row = slot >> 3, dg = (slot & 7) << 3;
      const size_t gbase = (size_t)(b * SB + kt0 + row) * 3072 + hh * 64 + dg;
      *(bf16x8*)&Ks[row][dg ^ ((row & 7) << 3)] =
          *(const bf16x8*)&qkv[gbase + 1024];
      *(bf16x8*)&Vs[row][dg] =
          *(const bf16x8*)&qkv[gbase + 2048];
    }
    __syncthreads();

    // S tile = Q @ K^T
    f32x4 s[4] = {};
    const int qrow = (w << 4) + l16;
#pragma unroll
    for (int ds = 0; ds < 2; ++ds) {
      const int cbase = (ds << 5) + (quad << 3);
      const bf16x8 af = *(const bf16x8*)&Qs[qrow][cbase ^ ((qrow & 7) << 3)];
#pragma unroll
      for (int nt = 0; nt < 4; ++nt) {
        const int krow = (nt << 4) + l16;
        const bf16x8 bfr = *(const bf16x8*)&Ks[krow][cbase ^ ((krow & 7) << 3)];
        s[nt] = __builtin_amdgcn_mfma_f32_16x16x32_bf16(af, bfr, s[nt], 0, 0, 0);
      }
    }
    // scale + key mask
#pragma unroll
    for (int nt = 0; nt < 4; ++nt) {
      const bool valid = (kt0 + (nt << 4) + l16) < len;
#pragma unroll
      for (int r = 0; r < 4; ++r)
        s[nt][r] = valid ? s[nt][r] * scale : -1e30f;
    }
    // row max
    float mt[4];
#pragma unroll
    for (int r = 0; r < 4; ++r)
      mt[r] = fmaxf(fmaxf(s[0][r], s[1][r]), fmaxf(s[2][r], s[3][r]));
#pragma unroll
    for (int off = 1; off < 16; off <<= 1)
#pragma unroll
      for (int r = 0; r < 4; ++r)
        mt[r] = fmaxf(mt[r], __shfl_xor(mt[r], off));
    float alpha[4];
#pragma unroll
    for (int r = 0; r < 4; ++r) {
      const float mn = fmaxf(m_i[r], mt[r]);
      alpha[r] = __expf(m_i[r] - mn);
      m_i[r] = mn;
    }
    // exponentiate + row sums
    float rs[4] = {0.f, 0.f, 0.f, 0.f};
#pragma unroll
    for (int nt = 0; nt < 4; ++nt)
#pragma unroll
      for (int r = 0; r < 4; ++r) {
        const float pe = __expf(s[nt][r] - m_i[r]);
        s[nt][r] = pe;
        rs[r] += pe;
      }
#pragma unroll
    for (int off = 1; off < 16; off <<= 1)
#pragma unroll
      for (int r = 0; r < 4; ++r)
        rs[r] += __shfl_xor(rs[r], off);
#pragma unroll
    for (int r = 0; r < 4; ++r) l_i[r] = l_i[r] * alpha[r] + rs[r];
    // P (C-layout) -> LDS (A-layout, swizzled), rescale O
#pragma unroll
    for (int nt = 0; nt < 4; ++nt)
#pragma unroll
      for (int r = 0; r < 4; ++r) {
        const int prow = (quad << 2) + r;
        Ps[w][prow][((nt << 4) + l16) ^ ((prow & 7) << 3)] = (bf16)s[nt][r];
        Oacc[nt][r] *= alpha[r];
      }
    // transpose Vs[kk][dv] -> Vt[dv][kk] (swizzled), all inside LDS
#pragma unroll
    for (int r2 = 0; r2 < 2; ++r2) {
      const int dv = tid & 63;
      const int kg2 = ((tid >> 6) << 3) + (r2 << 5);
      bf16x8 vv;
#pragma unroll
      for (int u = 0; u < 8; ++u)
        vv[u] = Vs[kg2 + u][dv];
      *(bf16x8*)&Vt[dv][kg2 ^ ((dv & 7) << 3)] = vv;
    }
    __syncthreads();
    // O += P @ V
#pragma unroll
    for (int ks = 0; ks < 2; ++ks) {
      const int cbase = (ks << 5) + (quad << 3);
      const bf16x8 af = *(const bf16x8*)&Ps[w][l16][cbase ^ ((l16 & 7) << 3)];
#pragma unroll
      for (int nt = 0; nt < 4; ++nt) {
        const int vrow = (nt << 4) + l16;
        const bf16x8 bfr = *(const bf16x8*)&Vt[vrow][cbase ^ ((vrow & 7) << 3)];
        Oacc[nt] = __builtin_amdgcn_mfma_f32_16x16x32_bf16(af, bfr, Oacc[nt], 0, 0, 0);
      }
    }
  }
  // epilogue
  float inv[4];
#pragma unroll
  for (int r = 0; r < 4; ++r) inv[r] = 1.0f / l_i[r];
#pragma unroll
  for (int nt = 0; nt < 4; ++nt)
#pragma unroll
    for (int r = 0; r < 4; ++r) {
      const int row = b * SB + q0 + (w << 4) + (quad << 2) + r;
      const int col = hh * 64 + (nt << 4) + l16;
      o[(size_t)row * 1024 + col] = (bf16)(Oacc[nt][r] * inv[r]);
    }
}

extern "C" void kernel_launch(void* const* d_in, const int* in_sizes, int n_in,
                              void* d_out, int out_size, void* d_ws, size_t ws_size,
                              hipStream_t stream) {
  const int*   tokens = (const int*)  d_in[0];
  const int*   lengths= (const int*)  d_in[1];
  const float* emb    = (const float*)d_in[2];
  const float* Wq     = (const float*)d_in[3];
  const float* bq     = (const float*)d_in[4];
  const float* Wkv    = (const float*)d_in[5];
  const float* bkv    = (const float*)d_in[6];
  const float* Wo     = (const float*)d_in[7];
  const float* bo     = (const float*)d_in[8];
  const float* lag    = (const float*)d_in[9];
  const float* lab    = (const float*)d_in[10];
  const float* W1     = (const float*)d_in[11];
  const float* b1     = (const float*)d_in[12];
  const float* W2     = (const float*)d_in[13];
  const float* b2     = (const float*)d_in[14];
  const float* lfg    = (const float*)d_in[15];  // ln_ffn_g
  const float* lfb    = (const float*)d_in[16];  // ln_ffn_b
  const float* lgf    = (const float*)d_in[17];  // ln_f_g
  const float* lbf    = (const float*)d_in[18];  // ln_f_b

  char* p = (char*)d_ws;
  float* x     = (float*)p; p += (size_t)4096 * 1024 * 4;   // residual f32 (16MB)
  bf16*  h     = (bf16*)p;  p += (size_t)4096 * 1024 * 2;   // LN out (8MB)
  bf16*  qkv   = (bf16*)p;  p += (size_t)4096 * 3072 * 2;   // fused QKV (24MB)
  bf16*  o     = (bf16*)p;  p += (size_t)4096 * 1024 * 2;   // attn out (8MB)
  bf16*  mid   = (bf16*)p;  p += (size_t)4096 * 4096 * 2;   // FFN mid (32MB)
  bf16*  wqkvt = (bf16*)p;  p += (size_t)3072 * 1024 * 2;   // Wqkv^T (6MB)
  bf16*  wot   = (bf16*)p;  p += (size_t)1024 * 1024 * 2;   // Wo^T (2MB)
  bf16*  w1t   = (bf16*)p;  p += (size_t)4096 * 1024 * 2;   // W1^T (8MB)
  bf16*  w2t   = (bf16*)p;  p += (size_t)1024 * 4096 * 2;   // W2^T (8MB)
  float* bqkv  = (float*)p; p += (size_t)6 * 3072 * 4;      // concat bias
  p = (char*)(((size_t)p + 255) & ~(size_t)255);
  float* part  = (float*)p; p += (size_t)4 * 4096 * 1024 * 4; // split-K partials (64MB)

  bias_concat_kernel<<<72, 256, 0, stream>>>(bq, bkv, bqkv);
  embed_kernel<<<4096, 256, 0, stream>>>(tokens, emb, x);

  for (int l = 0; l < 6; ++l) {
    // per-layer weight transpose+convert (bf16, [N][K])
    wtrans_kernel<<<dim3(16, 16), 256, 0, stream>>>(
        Wq + (size_t)l * 1024 * 1024, wqkvt, 1024, 1024);
    wtrans_kernel<<<dim3(32, 16), 256, 0, stream>>>(
        Wkv + (size_t)l * 1024 * 2048, wqkvt + (size_t)1024 * 1024, 2048, 1024);
    wtrans_kernel<<<dim3(16, 16), 256, 0, stream>>>(
        Wo + (size_t)l * 1024 * 1024, wot, 1024, 1024);
    wtrans_kernel<<<dim3(64, 16), 256, 0, stream>>>(
        W1 + (size_t)l * 1024 * 4096, w1t, 4096, 1024);
    wtrans_kernel<<<dim3(16, 64), 256, 0, stream>>>(
        W2 + (size_t)l * 4096 * 1024, w2t, 1024, 4096);

    // --- attn sublayer ---
    if (l == 0) {
      ln_kernel<true><<<4096, 256, 0, stream>>>(
          x, lag, lab, h, nullptr);
    } else {
      // reduce previous layer's W2 partials (+b2_{l-1}) into x, then ln_attn
      red_ln_kernel<4, true, true><<<4096, 256, 0, stream>>>(
          x, part, b2 + (size_t)(l - 1) * 1024,
          lag + (size_t)l * 1024, lab + (size_t)l * 1024, x, h, nullptr);
    }
    gemm256<false, true, false><<<dim3(12, 16), 512, 0, stream>>>(
        h, wqkvt, bqkv + (size_t)l * 3072, qkv, nullptr, 4096, 3072, 1024);
    attn_kernel<<<dim3(8, 16, 8), 256, 0, stream>>>(qkv, lengths, o);
    // attn-out projection, split-K=4 -> partials (grid 256 blocks)
    gemm256<false, false, true><<<dim3(4, 16, 4), 512, 0, stream>>>(
        o, wot, nullptr, nullptr, part, 4096, 1024, 1024);
    // --- FFN sublayer ---
    // reduce Wo partials (+bo) into x, then ln_ffn
    red_ln_kernel<4, true, true><<<4096, 256, 0, stream>>>(
        x, part, bo + (size_t)l * 1024,
        lfg + (size_t)l * 1024, lfb + (size_t)l * 1024, x, h, nullptr);
    gemm256<true, true, false><<<dim3(16, 16), 512, 0, stream>>>(
        h, w1t, b1 + (size_t)l * 4096, mid, nullptr, 4096, 4096, 1024);
    // FFN down projection, split-K=4 -> partials (grid 256 blocks)
    gemm256<false, false, true><<<dim3(4, 16, 4), 512, 0, stream>>>(
        mid, w2t, nullptr, nullptr, part, 4096, 1024, 4096);
  }
  // final: reduce layer-5 W2 partials (+b2_5) and apply ln_f -> d_out (f32)
  red_ln_kernel<4, false, false><<<4096, 256, 0, stream>>>(
      x, part, b2 + (size_t)5 * 1024, lgf, lbf, nullptr, nullptr, (float*)d_out);
}